// Round 1
// baseline (556.591 us; speedup 1.0000x reference)
//
#include <hip/hip_runtime.h>
#include <math.h>

#define NBN 64      // B*N_HEADS
#define DD  64      // head dim
#define SS  1024    // sequence length (H*W)

#if defined(__has_builtin)
#  if __has_builtin(__builtin_amdgcn_sdot4)
#    define HAVE_SDOT4 1
#  endif
#endif
#ifndef HAVE_SDOT4
#  define HAVE_SDOT4 0
#endif

__device__ __forceinline__ int dot4(int a, int b, int c) {
#if HAVE_SDOT4
    return __builtin_amdgcn_sdot4(a, b, c, false);
#else
    c += ((a << 24) >> 24) * ((b << 24) >> 24);
    c += ((a << 16) >> 24) * ((b << 16) >> 24);
    c += ((a <<  8) >> 24) * ((b <<  8) >> 24);
    c += ( a        >> 24) * ( b        >> 24);
    return c;
#endif
}

__device__ __forceinline__ float mkscale(unsigned bits, float qmax) {
    // matches: jnp.maximum(absmax / qmax, 1e-8)
    return fmaxf(__uint_as_float(bits) / qmax, 1e-8f);
}

__device__ __forceinline__ int quant_sym(float x, float sc) {
    // matches: clip(round(x/sc), -127, 127) with round-half-even (v_rndne)
    float r = fminf(fmaxf(rintf(x / sc), -127.0f), 127.0f);
    return (int)r;
}

__global__ void k_init(unsigned* st) {
    if (threadIdx.x == 0) { st[0]=0u; st[1]=0u; st[2]=0u; st[3]=0x7F800000u; } // minl = +inf
}

__global__ void k_absmax(const float* __restrict__ q, const float* __restrict__ k,
                         const float* __restrict__ v, unsigned* __restrict__ st) {
    const float* src = (blockIdx.y == 0) ? q : (blockIdx.y == 1) ? k : v;
    const int n = NBN * DD * SS;  // 4,194,304
    float m = 0.0f;
    for (int i = (blockIdx.x * 256 + threadIdx.x) * 4; i < n; i += gridDim.x * 256 * 4) {
        float4 x = *(const float4*)(src + i);
        m = fmaxf(m, fmaxf(fmaxf(fabsf(x.x), fabsf(x.y)), fmaxf(fabsf(x.z), fabsf(x.w))));
    }
    __shared__ float red[256];
    red[threadIdx.x] = m;
    __syncthreads();
    for (int off = 128; off > 0; off >>= 1) {
        if (threadIdx.x < off) red[threadIdx.x] = fmaxf(red[threadIdx.x], red[threadIdx.x + off]);
        __syncthreads();
    }
    if (threadIdx.x == 0) atomicMax(st + blockIdx.y, __float_as_uint(red[0]));
}

// Q,K: quantize + transpose-pack: Qp[bn][s][j] = pack_i8(iq[4j..4j+3][s]), j=0..15
__global__ void k_quant_qk(const float* __restrict__ q, const float* __restrict__ k,
                           const unsigned* __restrict__ st,
                           int* __restrict__ Qp, int* __restrict__ Kp) {
    const int which = blockIdx.z;                 // 0=q, 1=k
    const float* src = which ? k : q;
    int* dst = which ? Kp : Qp;
    const float sc = mkscale(st[which], 127.0f);
    const int bn = blockIdx.y;
    const int s = blockIdx.x * 256 + threadIdx.x;
    const float* tsrc = src + (size_t)bn * DD * SS;
    int4* tdst4 = (int4*)(dst + ((size_t)bn * SS + s) * 16);
    #pragma unroll
    for (int jj = 0; jj < 4; ++jj) {
        int pw[4];
        #pragma unroll
        for (int u = 0; u < 4; ++u) {
            const int j = jj * 4 + u;
            int p = 0;
            #pragma unroll
            for (int r = 0; r < 4; ++r) {
                int iq = quant_sym(tsrc[(size_t)(4 * j + r) * SS + s], sc);
                p |= (iq & 0xff) << (8 * r);
            }
            pw[u] = p;
        }
        tdst4[jj] = make_int4(pw[0], pw[1], pw[2], pw[3]);
    }
}

// V: quantize + pack along t:  Vp[bn][jt][dd] = pack_i8(iv[dd][4jt..4jt+3]), jt=0..255
__global__ void k_quant_v(const float* __restrict__ v, const unsigned* __restrict__ st,
                          int* __restrict__ Vp) {
    __shared__ int Tl[64][65];
    const float sc = mkscale(st[2], 127.0f);
    const int bn = blockIdx.y, jtb = blockIdx.x;
    for (int i = threadIdx.x; i < 4096; i += 256) {
        int jt = i & 63, dd = i >> 6;
        float4 x = *(const float4*)(v + (size_t)(bn * DD + dd) * SS + (size_t)(jtb * 64 + jt) * 4);
        int p =  (quant_sym(x.x, sc) & 0xff)
              | ((quant_sym(x.y, sc) & 0xff) << 8)
              | ((quant_sym(x.z, sc) & 0xff) << 16)
              | ((quant_sym(x.w, sc) & 0xff) << 24);
        Tl[jt][dd] = p;
    }
    __syncthreads();
    for (int i = threadIdx.x; i < 4096; i += 256) {
        int dd = i & 63, jt = i >> 6;
        Vp[((size_t)bn * 256 + jtb * 64 + jt) * 64 + dd] = Tl[jt][dd];
    }
}

// Phase A: per row, softmax max m and denom l (online), plus global min(l).
__global__ __launch_bounds__(256) void k_phase_a(const int* __restrict__ Qp,
    const int* __restrict__ Kp, const unsigned* __restrict__ st,
    float* __restrict__ m_arr, float* __restrict__ l_arr, unsigned* __restrict__ minl) {
    __shared__ int Kl[512 * 16];     // half of K, 32 KB
    const int bn = blockIdx.y;
    const int s = blockIdx.x * 256 + threadIdx.x;
    const float sq = mkscale(st[0], 127.0f);
    const float sk = mkscale(st[1], 127.0f);
    const float cqk = (sq * sk) * 0.125f;   // *0.125 is exact (pow2)
    int qp[16];
    {
        const int4* qr = (const int4*)(Qp + ((size_t)bn * SS + s) * 16);
        int4 a0 = qr[0], a1 = qr[1], a2 = qr[2], a3 = qr[3];
        qp[0]=a0.x; qp[1]=a0.y; qp[2]=a0.z; qp[3]=a0.w;
        qp[4]=a1.x; qp[5]=a1.y; qp[6]=a1.z; qp[7]=a1.w;
        qp[8]=a2.x; qp[9]=a2.y; qp[10]=a2.z; qp[11]=a2.w;
        qp[12]=a3.x; qp[13]=a3.y; qp[14]=a3.z; qp[15]=a3.w;
    }
    float m = -INFINITY, l = 0.0f;
    for (int half = 0; half < 2; ++half) {
        __syncthreads();
        const int4* src4 = (const int4*)(Kp + ((size_t)bn * SS + half * 512) * 16);
        int4* dst4 = (int4*)Kl;
        for (int i = threadIdx.x; i < 512 * 16 / 4; i += 256) dst4[i] = src4[i];
        __syncthreads();
        for (int t = 0; t < 512; ++t) {
            const int4* kr = (const int4*)(Kl + t * 16);
            int4 k0 = kr[0], k1 = kr[1], k2 = kr[2], k3 = kr[3];
            int s0 = dot4(qp[0],  k0.x, 0);  s0 = dot4(qp[1],  k0.y, s0);
            s0     = dot4(qp[2],  k0.z, s0); s0 = dot4(qp[3],  k0.w, s0);
            int s1 = dot4(qp[4],  k1.x, 0);  s1 = dot4(qp[5],  k1.y, s1);
            s1     = dot4(qp[6],  k1.z, s1); s1 = dot4(qp[7],  k1.w, s1);
            int s2 = dot4(qp[8],  k2.x, 0);  s2 = dot4(qp[9],  k2.y, s2);
            s2     = dot4(qp[10], k2.z, s2); s2 = dot4(qp[11], k2.w, s2);
            int s3 = dot4(qp[12], k3.x, 0);  s3 = dot4(qp[13], k3.y, s3);
            s3     = dot4(qp[14], k3.z, s3); s3 = dot4(qp[15], k3.w, s3);
            int ai = (s0 + s1) + (s2 + s3);
            float a = (float)ai * cqk;
            if (a > m) { l = l * expf(m - a); m = a; }
            l += expf(a - m);
        }
    }
    m_arr[bn * SS + s] = m;
    l_arr[bn * SS + s] = l;
    atomicMin(minl, __float_as_uint(l));   // l > 0: uint order == float order
}

// Phase B: recompute attn, P -> k1 -> LUT -> k2, pack 4 t's, int8 dot into 64 accumulators.
__global__ __launch_bounds__(256) void k_phase_b(const int* __restrict__ Qp,
    const int* __restrict__ Kp, const int* __restrict__ Vp,
    const unsigned* __restrict__ st, const float* __restrict__ m_arr,
    const float* __restrict__ l_arr, const unsigned* __restrict__ minl,
    float* __restrict__ out) {
    __shared__ int Kl[256 * 16];    // quarter of K, 16 KB
    __shared__ int Vl[64 * 64];     // quarter of V  [tg][dd], 16 KB
    __shared__ int lut[256];        // k1 -> k2
    const int bn = blockIdx.y;
    const int tid = threadIdx.x;
    const int s = blockIdx.x * 256 + tid;
    const float sq = mkscale(st[0], 127.0f);
    const float sk = mkscale(st[1], 127.0f);
    const float sv = mkscale(st[2], 127.0f);
    const float cqk = (sq * sk) * 0.125f;
    // scale chain replicated with the reference's exact float roundings:
    const float maxP     = 1.0f / __uint_as_float(*minl);       // max of softmax tensor
    const float scale_p  = fmaxf(maxP / 255.0f, 1e-8f);          // fq_unsigned scale
    const float maxP1    = 255.0f * scale_p;                     // max of P1
    const float scale_p2 = fmaxf(maxP1 / 127.0f, 1e-8f);         // fq_sym scale on P1
    {
        float P1 = (float)tid * scale_p;
        float x = P1 / scale_p2;
        lut[tid] = (int)fminf(fmaxf(rintf(x), -127.0f), 127.0f);
    }
    const float m = m_arr[bn * SS + s];
    const float l = l_arr[bn * SS + s];
    int qp[16];
    {
        const int4* qr = (const int4*)(Qp + ((size_t)bn * SS + s) * 16);
        int4 a0 = qr[0], a1 = qr[1], a2 = qr[2], a3 = qr[3];
        qp[0]=a0.x; qp[1]=a0.y; qp[2]=a0.z; qp[3]=a0.w;
        qp[4]=a1.x; qp[5]=a1.y; qp[6]=a1.z; qp[7]=a1.w;
        qp[8]=a2.x; qp[9]=a2.y; qp[10]=a2.z; qp[11]=a2.w;
        qp[12]=a3.x; qp[13]=a3.y; qp[14]=a3.z; qp[15]=a3.w;
    }
    int acc[64];
    #pragma unroll
    for (int d = 0; d < 64; ++d) acc[d] = 0;
    for (int qq = 0; qq < 4; ++qq) {
        __syncthreads();
        {
            const int4* ks4 = (const int4*)(Kp + ((size_t)bn * SS + qq * 256) * 16);
            int4* kd4 = (int4*)Kl;
            for (int i = tid; i < 256 * 16 / 4; i += 256) kd4[i] = ks4[i];
            const int4* vs4 = (const int4*)(Vp + ((size_t)bn * 256 + qq * 64) * 64);
            int4* vd4 = (int4*)Vl;
            for (int i = tid; i < 64 * 64 / 4; i += 256) vd4[i] = vs4[i];
        }
        __syncthreads();
        for (int tg = 0; tg < 64; ++tg) {
            int p4 = 0;
            #pragma unroll
            for (int r = 0; r < 4; ++r) {
                const int4* kr = (const int4*)(Kl + (tg * 4 + r) * 16);
                int4 k0 = kr[0], k1v = kr[1], k2v = kr[2], k3v = kr[3];
                int s0 = dot4(qp[0],  k0.x, 0);   s0 = dot4(qp[1],  k0.y, s0);
                s0     = dot4(qp[2],  k0.z, s0);  s0 = dot4(qp[3],  k0.w, s0);
                int s1 = dot4(qp[4],  k1v.x, 0);  s1 = dot4(qp[5],  k1v.y, s1);
                s1     = dot4(qp[6],  k1v.z, s1); s1 = dot4(qp[7],  k1v.w, s1);
                int s2 = dot4(qp[8],  k2v.x, 0);  s2 = dot4(qp[9],  k2v.y, s2);
                s2     = dot4(qp[10], k2v.z, s2); s2 = dot4(qp[11], k2v.w, s2);
                int s3 = dot4(qp[12], k3v.x, 0);  s3 = dot4(qp[13], k3v.y, s3);
                s3     = dot4(qp[14], k3v.z, s3); s3 = dot4(qp[15], k3v.w, s3);
                int ai = (s0 + s1) + (s2 + s3);
                float a = (float)ai * cqk;            // bit-identical to phase A
                float e = expf(a - m);                // == 1.0 at the row max
                float P = e / l;                      // IEEE div, matches ref softmax
                float x = P / scale_p;                // IEEE div, matches fq_unsigned
                int k1 = (int)fminf(fmaxf(rintf(x), 0.0f), 255.0f);
                p4 |= (lut[k1] & 0xff) << (8 * r);
            }
            const int4* vr = (const int4*)(Vl + tg * 64);
            #pragma unroll
            for (int j = 0; j < 16; ++j) {
                int4 vv = vr[j];
                acc[4*j+0] = dot4(p4, vv.x, acc[4*j+0]);
                acc[4*j+1] = dot4(p4, vv.y, acc[4*j+1]);
                acc[4*j+2] = dot4(p4, vv.z, acc[4*j+2]);
                acc[4*j+3] = dot4(p4, vv.w, acc[4*j+3]);
            }
        }
    }
    const float cpv = scale_p2 * sv;
    float* obase = out + (size_t)bn * DD * SS + s;
    #pragma unroll
    for (int d = 0; d < 64; ++d) obase[(size_t)d * SS] = (float)acc[d] * cpv;
}

extern "C" void kernel_launch(void* const* d_in, const int* in_sizes, int n_in,
                              void* d_out, int out_size, void* d_ws, size_t ws_size,
                              hipStream_t stream) {
    const float* q = (const float*)d_in[0];
    const float* k = (const float*)d_in[1];
    const float* v = (const float*)d_in[2];
    float* out = (float*)d_out;
    char* ws = (char*)d_ws;

    unsigned* st = (unsigned*)ws;                                // [0]=amax_q [1]=amax_k [2]=amax_v [3]=min_l
    int* Qp      = (int*)(ws + 1024);                            // 4 MB: [bn][s][16] packed along d
    int* Kp      = (int*)(ws + 1024 + (size_t)(1 << 22));        // 4 MB
    int* Vp      = (int*)(ws + 1024 + (size_t)(2 << 22));        // 4 MB: [bn][jt][dd] packed along t
    float* m_arr = (float*)(ws + 1024 + (size_t)(3 << 22));      // 256 KB
    float* l_arr = (float*)(ws + 1024 + (size_t)(3 << 22) + (1 << 18)); // 256 KB

    k_init<<<1, 64, 0, stream>>>(st);
    k_absmax<<<dim3(256, 3), 256, 0, stream>>>(q, k, v, st);
    k_quant_qk<<<dim3(4, NBN, 2), 256, 0, stream>>>(q, k, st, Qp, Kp);
    k_quant_v<<<dim3(4, NBN), 256, 0, stream>>>(v, st, Vp);
    k_phase_a<<<dim3(4, NBN), 256, 0, stream>>>(Qp, Kp, st, m_arr, l_arr, st + 3);
    k_phase_b<<<dim3(4, NBN), 256, 0, stream>>>(Qp, Kp, Vp, st, m_arr, l_arr, st + 3, out);
}

// Round 2
// 160.350 us; speedup vs baseline: 3.4711x; 3.4711x over previous
//
#include <hip/hip_runtime.h>
#include <math.h>

#define NBN 64      // B*N_HEADS
#define DD  64      // head dim
#define SS  1024    // sequence length (H*W)

typedef int i32x4_ __attribute__((ext_vector_type(4)));

__device__ __forceinline__ i32x4_ mfma_i8(i32x4_ a, i32x4_ b, i32x4_ c) {
    // D[m][n] += sum_k A[m][k]*B[n][k] ; A/B: lane: m/n = lane&15, k = (lane>>4)*16 + reg*4 + byte
    // C/D: col(n) = lane&15, row(m) = (lane>>4)*4 + reg   [dtype-independent, verified layout]
    return __builtin_amdgcn_mfma_i32_16x16x64_i8(a, b, c, 0, 0, 0);
}

__device__ __forceinline__ float mkscale(unsigned bits, float qmax) {
    // matches: jnp.maximum(absmax / qmax, 1e-8)
    return fmaxf(__uint_as_float(bits) / qmax, 1e-8f);
}

__device__ __forceinline__ int quant_sym(float x, float sc) {
    // matches: clip(round(x/sc), -127, 127) with round-half-even (v_rndne)
    float r = fminf(fmaxf(rintf(x / sc), -127.0f), 127.0f);
    return (int)r;
}

__global__ void k_init(unsigned* st) {
    if (threadIdx.x == 0) { st[0]=0u; st[1]=0u; st[2]=0u; st[3]=0x7F800000u; } // minl = +inf
}

__global__ void k_absmax(const float* __restrict__ q, const float* __restrict__ k,
                         const float* __restrict__ v, unsigned* __restrict__ st) {
    const float* src = (blockIdx.y == 0) ? q : (blockIdx.y == 1) ? k : v;
    const int n = NBN * DD * SS;
    float m = 0.0f;
    for (int i = (blockIdx.x * 256 + threadIdx.x) * 4; i < n; i += gridDim.x * 256 * 4) {
        float4 x = *(const float4*)(src + i);
        m = fmaxf(m, fmaxf(fmaxf(fabsf(x.x), fabsf(x.y)), fmaxf(fabsf(x.z), fabsf(x.w))));
    }
    __shared__ float red[256];
    red[threadIdx.x] = m;
    __syncthreads();
    for (int off = 128; off > 0; off >>= 1) {
        if (threadIdx.x < off) red[threadIdx.x] = fmaxf(red[threadIdx.x], red[threadIdx.x + off]);
        __syncthreads();
    }
    if (threadIdx.x == 0) atomicMax(st + blockIdx.y, __float_as_uint(red[0]));
}

// Q,K: quantize + transpose-pack: Qp[bn][s][j] = pack_i8(iq[4j..4j+3][s]), j=0..15
__global__ void k_quant_qk(const float* __restrict__ q, const float* __restrict__ k,
                           const unsigned* __restrict__ st,
                           int* __restrict__ Qp, int* __restrict__ Kp) {
    const int which = blockIdx.z;
    const float* src = which ? k : q;
    int* dst = which ? Kp : Qp;
    const float sc = mkscale(st[which], 127.0f);
    const int bn = blockIdx.y;
    const int s = blockIdx.x * 256 + threadIdx.x;
    const float* tsrc = src + (size_t)bn * DD * SS;
    int4* tdst4 = (int4*)(dst + ((size_t)bn * SS + s) * 16);
    #pragma unroll
    for (int jj = 0; jj < 4; ++jj) {
        int pw[4];
        #pragma unroll
        for (int u = 0; u < 4; ++u) {
            const int j = jj * 4 + u;
            int p = 0;
            #pragma unroll
            for (int r = 0; r < 4; ++r) {
                int iq = quant_sym(tsrc[(size_t)(4 * j + r) * SS + s], sc);
                p |= (iq & 0xff) << (8 * r);
            }
            pw[u] = p;
        }
        tdst4[jj] = make_int4(pw[0], pw[1], pw[2], pw[3]);
    }
}

// V: quantize + pack into PV B-fragment order:
// Vq word at (bn*16+tb)*1024 + dt*256 + g*64 + dc*4 + u  =  pack_i8(V[t = tb*64+g*16+u*4+0..3][d = dt*16+dc])
__global__ void k_quant_v(const float* __restrict__ v, const unsigned* __restrict__ st,
                          int* __restrict__ Vq) {
    __shared__ __align__(16) int Tl[64][20];
    const float sc = mkscale(st[2], 127.0f);
    const int bn = blockIdx.y, tb = blockIdx.x;
    const int tid = threadIdx.x;
    {
        const int d = tid >> 2, tqq = tid & 3;
        #pragma unroll
        for (int i = 0; i < 4; ++i) {
            const int tq = tqq * 4 + i;
            float4 x = *(const float4*)(v + (size_t)(bn * 64 + d) * SS + tb * 64 + tq * 4);
            Tl[d][tq] = (quant_sym(x.x, sc) & 0xff)
                      | ((quant_sym(x.y, sc) & 0xff) << 8)
                      | ((quant_sym(x.z, sc) & 0xff) << 16)
                      | ((quant_sym(x.w, sc) & 0xff) << 24);
        }
    }
    __syncthreads();
    {
        const int dt = tid >> 6, gg = (tid >> 4) & 3;
        const int d = dt * 16 + (tid & 15);
        int4 w = make_int4(Tl[d][gg*4+0], Tl[d][gg*4+1], Tl[d][gg*4+2], Tl[d][gg*4+3]);
        *(int4*)(Vq + (size_t)(bn * 16 + tb) * 1024 + tid * 4) = w;
    }
}

// Phase A: swapped QK^T via MFMA; per-lane online (m,l) for fixed s = lane&15; combine across 4 g-groups.
__global__ __launch_bounds__(256) void k_phase_a(const int* __restrict__ Qp,
    const int* __restrict__ Kp, const unsigned* __restrict__ st,
    float* __restrict__ m2_arr, float* __restrict__ l_arr, unsigned* __restrict__ minl)
{
    const int bn = blockIdx.y;
    const int wv = threadIdx.x >> 6, lane = threadIdx.x & 63;
    const int g = lane >> 4, c = lane & 15;
    const int s0 = blockIdx.x * 64 + wv * 16;
    const float sq = mkscale(st[0], 127.0f);
    const float sk = mkscale(st[1], 127.0f);
    const float cqk2 = (sq * sk * 0.125f) * 1.4426950408889634f;  // log2-domain scale
    const i32x4_ qf = *(const i32x4_*)(Qp + ((size_t)bn * SS + s0 + c) * 16 + g * 4);
    i32x4_ kf = *(const i32x4_*)(Kp + ((size_t)bn * SS + c) * 16 + g * 4);
    const i32x4_ zero = {0, 0, 0, 0};
    float m2 = -3.4e38f, l = 0.0f;
    for (int tt = 0; tt < 64; ++tt) {
        const int ttn = (tt < 63) ? tt + 1 : 63;
        i32x4_ kn = *(const i32x4_*)(Kp + ((size_t)bn * SS + ttn * 16 + c) * 16 + g * 4);
        i32x4_ dq = mfma_i8(kf, qf, zero);   // lane: s=c, t = tt*16 + 4g + r
        kf = kn;
        float a0 = (float)dq[0] * cqk2, a1 = (float)dq[1] * cqk2;
        float a2 = (float)dq[2] * cqk2, a3 = (float)dq[3] * cqk2;
        float t4 = fmaxf(fmaxf(a0, a1), fmaxf(a2, a3));
        if (t4 > m2) { l *= exp2f(m2 - t4); m2 = t4; }
        l += exp2f(a0 - m2) + exp2f(a1 - m2) + exp2f(a2 - m2) + exp2f(a3 - m2);
    }
    #pragma unroll
    for (int mk = 16; mk <= 32; mk <<= 1) {
        float mo = __shfl_xor(m2, mk, 64);
        float lo = __shfl_xor(l, mk, 64);
        float mn = fmaxf(m2, mo);
        l = l * exp2f(m2 - mn) + lo * exp2f(mo - mn);
        m2 = mn;
    }
    if (g == 0) {
        m2_arr[bn * SS + s0 + c] = m2;
        l_arr[bn * SS + s0 + c] = l;
    }
    float lm = l;
    #pragma unroll
    for (int mk = 1; mk <= 8; mk <<= 1) lm = fminf(lm, __shfl_xor(lm, mk, 64));
    if (lane == 0) atomicMin(minl, __float_as_uint(lm));   // l > 0: uint order == float order
}

// Phase B: QK^T (swapped) -> quantize P -> per-wave LDS word-transpose -> PV via MFMA.
__global__ __launch_bounds__(256) void k_phase_b(const int* __restrict__ Qp,
    const int* __restrict__ Kp, const int* __restrict__ Vq,
    const unsigned* __restrict__ st, const float* __restrict__ m2_arr,
    const float* __restrict__ l_arr, const unsigned* __restrict__ minl,
    float* __restrict__ out)
{
    __shared__ __align__(16) int Pl[4 * 320];   // per-wave 16 rows x 20-word stride (2-way max bank alias)
    const int bn = blockIdx.y;
    const int wv = threadIdx.x >> 6, lane = threadIdx.x & 63;
    const int g = lane >> 4, c = lane & 15;
    const int s0 = blockIdx.x * 64 + wv * 16;
    const float sq = mkscale(st[0], 127.0f);
    const float sk = mkscale(st[1], 127.0f);
    const float sv = mkscale(st[2], 127.0f);
    const float cqk2 = (sq * sk * 0.125f) * 1.4426950408889634f;
    const float maxP     = 1.0f / __uint_as_float(*minl);
    const float scale_p  = fmaxf(maxP / 255.0f, 1e-8f);
    const float scale_p2 = fmaxf((255.0f * scale_p) / 127.0f, 1e-8f);
    const float cpv = scale_p2 * sv;
    const float C2 = 127.0f / 255.0f;   // rint(k1*C2) == ref double-rounding chain (no half-integer within 2e-3)
    const float m2 = m2_arr[bn * SS + s0 + c];
    const float l  = l_arr [bn * SS + s0 + c];
    const float rlp = (1.0f / scale_p) / l;   // x = e * rlp
    const i32x4_ qf = *(const i32x4_*)(Qp + ((size_t)bn * SS + s0 + c) * 16 + g * 4);
    const i32x4_ zero = {0, 0, 0, 0};
    i32x4_ acc[4] = {zero, zero, zero, zero};
    i32x4_ kf = *(const i32x4_*)(Kp + ((size_t)bn * SS + c) * 16 + g * 4);
    int* myP = Pl + wv * 320;
    const int wbase = c * 20 + g * 4;

    for (int tb = 0; tb < 16; ++tb) {
        i32x4_ vf[4];
        #pragma unroll
        for (int dt = 0; dt < 4; ++dt)
            vf[dt] = *(const i32x4_*)(Vq + (size_t)(bn * 16 + tb) * 1024 + dt * 256 + g * 64 + c * 4);
        int W[4];
        #pragma unroll
        for (int j = 0; j < 4; ++j) {
            const int tt = tb * 4 + j;
            const int ttn = (tt < 63) ? tt + 1 : 63;
            i32x4_ kn = *(const i32x4_*)(Kp + ((size_t)bn * SS + ttn * 16 + c) * 16 + g * 4);
            i32x4_ dq = mfma_i8(kf, qf, zero);
            kf = kn;
            int w = 0;
            #pragma unroll
            for (int r = 0; r < 4; ++r) {
                float e = exp2f(fmaf((float)dq[r], cqk2, -m2));
                float x = e * rlp;
                float k1 = fminf(fmaxf(rintf(x), 0.0f), 255.0f);
                float k2 = fminf(rintf(k1 * C2), 127.0f);
                w |= ((int)k2) << (8 * r);
            }
            W[j] = w;
        }
        // word-transpose: lane (c,g) wrote W[j] (t-local 16j+4g+r); A-frag word u = W[g] of lane (c,u)
        i32x4_ wv4 = {W[0], W[1], W[2], W[3]};
        *(i32x4_*)(myP + wbase) = wv4;
        i32x4_ pa;
        pa[0] = myP[c * 20 + 0 * 4 + g];
        pa[1] = myP[c * 20 + 1 * 4 + g];
        pa[2] = myP[c * 20 + 2 * 4 + g];
        pa[3] = myP[c * 20 + 3 * 4 + g];
        #pragma unroll
        for (int dt = 0; dt < 4; ++dt) acc[dt] = mfma_i8(pa, vf[dt], acc[dt]);
    }
    // D: s = s0 + 4g + r, d = dt*16 + c
    float* ob = out + (size_t)bn * DD * SS + s0 + g * 4;
    #pragma unroll
    for (int dt = 0; dt < 4; ++dt) {
        #pragma unroll
        for (int r = 0; r < 4; ++r)
            ob[(size_t)(dt * 16 + c) * SS + r] = (float)acc[dt][r] * cpv;
    }
}

extern "C" void kernel_launch(void* const* d_in, const int* in_sizes, int n_in,
                              void* d_out, int out_size, void* d_ws, size_t ws_size,
                              hipStream_t stream) {
    const float* q = (const float*)d_in[0];
    const float* k = (const float*)d_in[1];
    const float* v = (const float*)d_in[2];
    float* out = (float*)d_out;
    char* ws = (char*)d_ws;

    unsigned* st = (unsigned*)ws;                                 // [0..2]=amax q,k,v  [3]=min_l
    int* Qp      = (int*)(ws + 1024);                             // 4 MB
    int* Kp      = (int*)(ws + 1024 + (size_t)(1 << 22));         // 4 MB
    int* Vq      = (int*)(ws + 1024 + (size_t)(2 << 22));         // 4 MB (B-fragment order)
    float* m2    = (float*)(ws + 1024 + (size_t)(3 << 22));       // 256 KB (log2-domain row max)
    float* l_a   = (float*)(ws + 1024 + (size_t)(3 << 22) + (1 << 18)); // 256 KB

    k_init<<<1, 64, 0, stream>>>(st);
    k_absmax<<<dim3(256, 3), 256, 0, stream>>>(q, k, v, st);
    k_quant_qk<<<dim3(4, NBN, 2), 256, 0, stream>>>(q, k, st, Qp, Kp);
    k_quant_v<<<dim3(16, NBN), 256, 0, stream>>>(v, st, Vq);
    k_phase_a<<<dim3(16, NBN), 256, 0, stream>>>(Qp, Kp, st, m2, l_a, st + 3);
    k_phase_b<<<dim3(16, NBN), 256, 0, stream>>>(Qp, Kp, Vq, st, m2, l_a, st + 3, out);
}

// Round 3
// 147.336 us; speedup vs baseline: 3.7777x; 1.0883x over previous
//
#include <hip/hip_runtime.h>
#include <math.h>

#define NBN 64      // B*N_HEADS
#define DD  64      // head dim
#define SS  1024    // sequence length (H*W)

typedef int i32x4_ __attribute__((ext_vector_type(4)));

__device__ __forceinline__ i32x4_ mfma_i8(i32x4_ a, i32x4_ b, i32x4_ c) {
    // D[m][n] += sum_k A[m][k]*B[n][k]; A/B lane: m/n = lane&15, k = (lane>>4)*16 + reg*4 + byte
    // C/D: col(n) = lane&15, row(m) = (lane>>4)*4 + reg
    return __builtin_amdgcn_mfma_i32_16x16x64_i8(a, b, c, 0, 0, 0);
}

__device__ __forceinline__ float mkscale(unsigned bits, float qmax) {
    return fmaxf(__uint_as_float(bits) / qmax, 1e-8f);   // jnp.maximum(absmax/qmax, 1e-8)
}

__device__ __forceinline__ int quant_sym(float x, float sc) {
    float r = fminf(fmaxf(rintf(x / sc), -127.0f), 127.0f);  // round-half-even == jnp.round
    return (int)r;
}

__global__ void k_init(unsigned* st) {
    if (threadIdx.x == 0) { st[0]=0u; st[1]=0u; st[2]=0u; st[3]=0x7F800000u; } // minl = +inf
}

__global__ void k_absmax(const float* __restrict__ q, const float* __restrict__ k,
                         const float* __restrict__ v, unsigned* __restrict__ st) {
    const float* src = (blockIdx.y == 0) ? q : (blockIdx.y == 1) ? k : v;
    const int n = NBN * DD * SS;
    float m = 0.0f;
    for (int i = (blockIdx.x * 256 + threadIdx.x) * 4; i < n; i += gridDim.x * 256 * 4) {
        float4 x = *(const float4*)(src + i);
        m = fmaxf(m, fmaxf(fmaxf(fabsf(x.x), fabsf(x.y)), fmaxf(fabsf(x.z), fabsf(x.w))));
    }
    __shared__ float red[256];
    red[threadIdx.x] = m;
    __syncthreads();
    for (int off = 128; off > 0; off >>= 1) {
        if (threadIdx.x < off) red[threadIdx.x] = fmaxf(red[threadIdx.x], red[threadIdx.x + off]);
        __syncthreads();
    }
    if (threadIdx.x == 0) atomicMax(st + blockIdx.y, __float_as_uint(red[0]));
}

// Q,K: quantize + transpose-pack: Qp[bn][s][j] = pack_i8(iq[4j..4j+3][s]), j=0..15
__global__ void k_quant_qk(const float* __restrict__ q, const float* __restrict__ k,
                           const unsigned* __restrict__ st,
                           int* __restrict__ Qp, int* __restrict__ Kp) {
    const int which = blockIdx.z;
    const float* src = which ? k : q;
    int* dst = which ? Kp : Qp;
    const float sc = mkscale(st[which], 127.0f);
    const int bn = blockIdx.y;
    const int s = blockIdx.x * 256 + threadIdx.x;
    const float* tsrc = src + (size_t)bn * DD * SS;
    int4* tdst4 = (int4*)(dst + ((size_t)bn * SS + s) * 16);
    #pragma unroll
    for (int jj = 0; jj < 4; ++jj) {
        int pw[4];
        #pragma unroll
        for (int u = 0; u < 4; ++u) {
            const int j = jj * 4 + u;
            int p = 0;
            #pragma unroll
            for (int r = 0; r < 4; ++r) {
                int iq = quant_sym(tsrc[(size_t)(4 * j + r) * SS + s], sc);
                p |= (iq & 0xff) << (8 * r);
            }
            pw[u] = p;
        }
        tdst4[jj] = make_int4(pw[0], pw[1], pw[2], pw[3]);
    }
}

// V: quantize + pack into PV B-fragment order.
__global__ void k_quant_v(const float* __restrict__ v, const unsigned* __restrict__ st,
                          int* __restrict__ Vq) {
    __shared__ __align__(16) int Tl[64][20];
    const float sc = mkscale(st[2], 127.0f);
    const int bn = blockIdx.y, tb = blockIdx.x;
    const int tid = threadIdx.x;
    {
        const int d = tid >> 2, tqq = tid & 3;
        #pragma unroll
        for (int i = 0; i < 4; ++i) {
            const int tq = tqq * 4 + i;
            float4 x = *(const float4*)(v + (size_t)(bn * 64 + d) * SS + tb * 64 + tq * 4);
            Tl[d][tq] = (quant_sym(x.x, sc) & 0xff)
                      | ((quant_sym(x.y, sc) & 0xff) << 8)
                      | ((quant_sym(x.z, sc) & 0xff) << 16)
                      | ((quant_sym(x.w, sc) & 0xff) << 24);
        }
    }
    __syncthreads();
    {
        const int dt = tid >> 6, gg = (tid >> 4) & 3;
        const int d = dt * 16 + (tid & 15);
        int4 w = make_int4(Tl[d][gg*4+0], Tl[d][gg*4+1], Tl[d][gg*4+2], Tl[d][gg*4+3]);
        *(int4*)(Vq + (size_t)(bn * 16 + tb) * 1024 + tid * 4) = w;
    }
}

// Phase A (two-pass): wave = 16 s-rows x 256 t's; dq kept in VGPRs.
// Pass 1: integer row-max (monotone map => matches float max). Pass 2: exp2 sum with final max.
__global__ __launch_bounds__(256) void k_phase_a(const int* __restrict__ Qp,
    const int* __restrict__ Kp, const unsigned* __restrict__ st,
    float* __restrict__ m2_arr, float* __restrict__ l_arr, unsigned* __restrict__ minl)
{
    __shared__ int   Mi[4][16];
    __shared__ float Lf[4][16];
    const int bn = blockIdx.y;
    const int wv = threadIdx.x >> 6, lane = threadIdx.x & 63;
    const int g = lane >> 4, c = lane & 15;
    const int s0 = blockIdx.x * 16;
    const float sq = mkscale(st[0], 127.0f);
    const float sk = mkscale(st[1], 127.0f);
    const float cqk2 = (sq * sk * 0.125f) * 1.4426950408889634f;  // log2-domain
    const i32x4_ qf = *(const i32x4_*)(Qp + ((size_t)bn * SS + s0 + c) * 16 + g * 4);
    const i32x4_ zero = {0, 0, 0, 0};
    const int t0 = wv * 256;
    const int* kbase = Kp + ((size_t)bn * SS + t0 + c) * 16 + g * 4;

    i32x4_ dq[16];
    #pragma unroll
    for (int j = 0; j < 16; ++j) {
        i32x4_ kf = *(const i32x4_*)(kbase + j * 256);
        dq[j] = mfma_i8(kf, qf, zero);   // lane: s = s0+c, t = t0 + 16j + 4g + r
    }
    int im = -2147483647;
    #pragma unroll
    for (int j = 0; j < 16; ++j) {
        int a01 = max(dq[j][0], dq[j][1]), a23 = max(dq[j][2], dq[j][3]);
        im = max(im, max(a01, a23));
    }
    im = max(im, __shfl_xor(im, 16, 64));
    im = max(im, __shfl_xor(im, 32, 64));
    if (g == 0) Mi[wv][c] = im;
    __syncthreads();
    im = max(max(Mi[0][c], Mi[1][c]), max(Mi[2][c], Mi[3][c]));
    const float m2 = (float)im * cqk2;    // = max of per-element fl(dq*cqk2) (monotone)
    float la = 0.0f, lb = 0.0f, lc = 0.0f, ld = 0.0f;
    #pragma unroll
    for (int j = 0; j < 16; ++j) {
        la += exp2f(fmaf((float)dq[j][0], cqk2, -m2));
        lb += exp2f(fmaf((float)dq[j][1], cqk2, -m2));
        lc += exp2f(fmaf((float)dq[j][2], cqk2, -m2));
        ld += exp2f(fmaf((float)dq[j][3], cqk2, -m2));
    }
    float l = (la + lb) + (lc + ld);
    l += __shfl_xor(l, 16, 64);
    l += __shfl_xor(l, 32, 64);
    if (g == 0) Lf[wv][c] = l;
    __syncthreads();
    if (threadIdx.x < 16) {
        const int cc = threadIdx.x;            // == c for wave 0 / g==0
        float lr = (Lf[0][cc] + Lf[1][cc]) + (Lf[2][cc] + Lf[3][cc]);
        m2_arr[bn * SS + s0 + cc] = m2;
        l_arr[bn * SS + s0 + cc] = lr;
        float lm = lr;
        #pragma unroll
        for (int mk = 1; mk <= 8; mk <<= 1) lm = fminf(lm, __shfl_xor(lm, mk, 64));
        if (cc == 0) atomicMin(minl, __float_as_uint(lm));  // l > 0: uint order == float order
    }
}

// Phase B: software-pipelined: ds_write(W[tb]) -> QK+quant(tb+1) hides LDS+global latency -> pa(tb) -> PV(tb).
__global__ __launch_bounds__(256) void k_phase_b(const int* __restrict__ Qp,
    const int* __restrict__ Kp, const int* __restrict__ Vq,
    const unsigned* __restrict__ st, const float* __restrict__ m2_arr,
    const float* __restrict__ l_arr, const unsigned* __restrict__ minl,
    float* __restrict__ out)
{
    __shared__ __align__(16) int Pl[4 * 320];   // per-wave 16 x 20-word stride
    const int bn = blockIdx.y;
    const int wv = threadIdx.x >> 6, lane = threadIdx.x & 63;
    const int g = lane >> 4, c = lane & 15;
    const int s0 = blockIdx.x * 64 + wv * 16;
    const float sq = mkscale(st[0], 127.0f);
    const float sk = mkscale(st[1], 127.0f);
    const float sv = mkscale(st[2], 127.0f);
    const float cqk2 = (sq * sk * 0.125f) * 1.4426950408889634f;
    const float maxP     = 1.0f / __uint_as_float(*minl);
    const float scale_p  = fmaxf(maxP / 255.0f, 1e-8f);
    const float scale_p2 = fmaxf((255.0f * scale_p) / 127.0f, 1e-8f);
    const float cpv = scale_p2 * sv;
    const float C2 = 127.0f / 255.0f;
    const float m2 = m2_arr[bn * SS + s0 + c];
    const float l  = l_arr [bn * SS + s0 + c];
    const float bexp = log2f((1.0f / scale_p) / l) - m2;   // x = exp2(dq*cqk2 + bexp)
    const i32x4_ qf = *(const i32x4_*)(Qp + ((size_t)bn * SS + s0 + c) * 16 + g * 4);
    const i32x4_ zero = {0, 0, 0, 0};
    const int* kbase = Kp + ((size_t)bn * SS + c) * 16 + g * 4;
    const int* vbase = Vq + (size_t)bn * 16384 + g * 64 + c * 4;
    int* myP = Pl + wv * 320;
    const int woff = c * 20 + g * 4;

    i32x4_ acc[4] = {zero, zero, zero, zero};
    i32x4_ vf[4], vn[4];
    #pragma unroll
    for (int dt = 0; dt < 4; ++dt) vf[dt] = *(const i32x4_*)(vbase + dt * 256);

    int W[4], N[4];
    #pragma unroll
    for (int j = 0; j < 4; ++j) {                       // prologue: W for tb=0
        i32x4_ kf = *(const i32x4_*)(kbase + (j * 16) * 16);
        i32x4_ dq = mfma_i8(kf, qf, zero);
        int w = 0;
        #pragma unroll
        for (int r = 0; r < 4; ++r) {
            float x = exp2f(fmaf((float)dq[r], cqk2, bexp));
            float k1 = fminf(rintf(x), 255.0f);          // x >= 0, so no lower clamp needed
            int k2 = (int)rintf(k1 * C2);                // <= 127 by construction
            w |= k2 << (8 * r);
        }
        W[j] = w;
    }

    for (int tb = 0; tb < 16; ++tb) {
        i32x4_ wv4 = {W[0], W[1], W[2], W[3]};
        *(i32x4_*)(myP + woff) = wv4;                    // publish W(tb)
        if (tb < 15) {
            const int* vb = vbase + (tb + 1) * 1024;
            #pragma unroll
            for (int dt = 0; dt < 4; ++dt) vn[dt] = *(const i32x4_*)(vb + dt * 256);
            #pragma unroll
            for (int j = 0; j < 4; ++j) {                // QK + quant for tb+1 (hides LDS latency)
                i32x4_ kf = *(const i32x4_*)(kbase + ((tb + 1) * 64 + j * 16) * 16);
                i32x4_ dq = mfma_i8(kf, qf, zero);
                int w = 0;
                #pragma unroll
                for (int r = 0; r < 4; ++r) {
                    float x = exp2f(fmaf((float)dq[r], cqk2, bexp));
                    float k1 = fminf(rintf(x), 255.0f);
                    int k2 = (int)rintf(k1 * C2);
                    w |= k2 << (8 * r);
                }
                N[j] = w;
            }
        }
        i32x4_ pa;                                       // word-transpose read: pa[u] = W[g] of lane (c,u)
        pa[0] = myP[c * 20 + 0 + g];
        pa[1] = myP[c * 20 + 4 + g];
        pa[2] = myP[c * 20 + 8 + g];
        pa[3] = myP[c * 20 + 12 + g];
        #pragma unroll
        for (int dt = 0; dt < 4; ++dt) acc[dt] = mfma_i8(pa, vf[dt], acc[dt]);
        #pragma unroll
        for (int dt = 0; dt < 4; ++dt) vf[dt] = vn[dt];
        #pragma unroll
        for (int j = 0; j < 4; ++j) W[j] = N[j];
    }
    // D: s = s0 + 4g + r, d = dt*16 + c
    float* ob = out + (size_t)bn * DD * SS + s0 + g * 4;
    #pragma unroll
    for (int dt = 0; dt < 4; ++dt) {
        #pragma unroll
        for (int r = 0; r < 4; ++r)
            ob[(size_t)(dt * 16 + c) * SS + r] = (float)acc[dt][r] * cpv;
    }
}

extern "C" void kernel_launch(void* const* d_in, const int* in_sizes, int n_in,
                              void* d_out, int out_size, void* d_ws, size_t ws_size,
                              hipStream_t stream) {
    const float* q = (const float*)d_in[0];
    const float* k = (const float*)d_in[1];
    const float* v = (const float*)d_in[2];
    float* out = (float*)d_out;
    char* ws = (char*)d_ws;

    unsigned* st = (unsigned*)ws;                                 // [0..2]=amax q,k,v  [3]=min_l
    int* Qp      = (int*)(ws + 1024);                             // 4 MB
    int* Kp      = (int*)(ws + 1024 + (size_t)(1 << 22));         // 4 MB
    int* Vq      = (int*)(ws + 1024 + (size_t)(2 << 22));         // 4 MB (B-fragment order)
    float* m2    = (float*)(ws + 1024 + (size_t)(3 << 22));       // 256 KB
    float* l_a   = (float*)(ws + 1024 + (size_t)(3 << 22) + (1 << 18)); // 256 KB

    k_init<<<1, 64, 0, stream>>>(st);
    k_absmax<<<dim3(256, 3), 256, 0, stream>>>(q, k, v, st);
    k_quant_qk<<<dim3(4, NBN, 2), 256, 0, stream>>>(q, k, st, Qp, Kp);
    k_quant_v<<<dim3(16, NBN), 256, 0, stream>>>(v, st, Vq);
    k_phase_a<<<dim3(64, NBN), 256, 0, stream>>>(Qp, Kp, st, m2, l_a, st + 3);
    k_phase_b<<<dim3(16, NBN), 256, 0, stream>>>(Qp, Kp, Vq, st, m2, l_a, st + 3, out);
}

// Round 4
// 141.752 us; speedup vs baseline: 3.9265x; 1.0394x over previous
//
#include <hip/hip_runtime.h>
#include <math.h>

#define NBN 64      // B*N_HEADS
#define DD  64      // head dim
#define SS  1024    // sequence length (H*W)

typedef int i32x4_ __attribute__((ext_vector_type(4)));

__device__ __forceinline__ i32x4_ mfma_i8(i32x4_ a, i32x4_ b, i32x4_ c) {
    // D[m][n] += sum_k A[m][k]*B[n][k]; A/B lane: m/n = lane&15, k = (lane>>4)*16 + reg*4 + byte
    // C/D: col(n) = lane&15, row(m) = (lane>>4)*4 + reg
    return __builtin_amdgcn_mfma_i32_16x16x64_i8(a, b, c, 0, 0, 0);
}

__device__ __forceinline__ float mkscale(unsigned bits, float qmax) {
    return fmaxf(__uint_as_float(bits) / qmax, 1e-8f);   // jnp.maximum(absmax/qmax, 1e-8)
}

__device__ __forceinline__ int quant_sym(float x, float sc) {
    float r = fminf(fmaxf(rintf(x / sc), -127.0f), 127.0f);  // round-half-even == jnp.round
    return (int)r;
}

__global__ void k_init(unsigned* st) {
    if (threadIdx.x == 0) { st[0]=0u; st[1]=0u; st[2]=0u; st[3]=0x7F800000u; } // minl = +inf
}

__global__ void k_absmax(const float* __restrict__ q, const float* __restrict__ k,
                         const float* __restrict__ v, unsigned* __restrict__ st) {
    const float* src = (blockIdx.y == 0) ? q : (blockIdx.y == 1) ? k : v;
    const int n = NBN * DD * SS;
    float m = 0.0f;
    for (int i = (blockIdx.x * 256 + threadIdx.x) * 4; i < n; i += gridDim.x * 256 * 4) {
        float4 x = *(const float4*)(src + i);
        m = fmaxf(m, fmaxf(fmaxf(fabsf(x.x), fabsf(x.y)), fmaxf(fabsf(x.z), fabsf(x.w))));
    }
    __shared__ float red[256];
    red[threadIdx.x] = m;
    __syncthreads();
    for (int off = 128; off > 0; off >>= 1) {
        if (threadIdx.x < off) red[threadIdx.x] = fmaxf(red[threadIdx.x], red[threadIdx.x + off]);
        __syncthreads();
    }
    if (threadIdx.x == 0) atomicMax(st + blockIdx.y, __float_as_uint(red[0]));
}

// Q,K: quantize + transpose-pack: Qp[bn][s][j] = pack_i8(iq[4j..4j+3][s]), j=0..15
__global__ void k_quant_qk(const float* __restrict__ q, const float* __restrict__ k,
                           const unsigned* __restrict__ st,
                           int* __restrict__ Qp, int* __restrict__ Kp) {
    const int which = blockIdx.z;
    const float* src = which ? k : q;
    int* dst = which ? Kp : Qp;
    const float sc = mkscale(st[which], 127.0f);
    const int bn = blockIdx.y;
    const int s = blockIdx.x * 256 + threadIdx.x;
    const float* tsrc = src + (size_t)bn * DD * SS;
    int4* tdst4 = (int4*)(dst + ((size_t)bn * SS + s) * 16);
    #pragma unroll
    for (int jj = 0; jj < 4; ++jj) {
        int pw[4];
        #pragma unroll
        for (int u = 0; u < 4; ++u) {
            const int j = jj * 4 + u;
            int p = 0;
            #pragma unroll
            for (int r = 0; r < 4; ++r) {
                int iq = quant_sym(tsrc[(size_t)(4 * j + r) * SS + s], sc);
                p |= (iq & 0xff) << (8 * r);
            }
            pw[u] = p;
        }
        tdst4[jj] = make_int4(pw[0], pw[1], pw[2], pw[3]);
    }
}

// V: quantize + pack into PV B-fragment order.
__global__ void k_quant_v(const float* __restrict__ v, const unsigned* __restrict__ st,
                          int* __restrict__ Vq) {
    __shared__ __align__(16) int Tl[64][20];
    const float sc = mkscale(st[2], 127.0f);
    const int bn = blockIdx.y, tb = blockIdx.x;
    const int tid = threadIdx.x;
    {
        const int d = tid >> 2, tqq = tid & 3;
        #pragma unroll
        for (int i = 0; i < 4; ++i) {
            const int tq = tqq * 4 + i;
            float4 x = *(const float4*)(v + (size_t)(bn * 64 + d) * SS + tb * 64 + tq * 4);
            Tl[d][tq] = (quant_sym(x.x, sc) & 0xff)
                      | ((quant_sym(x.y, sc) & 0xff) << 8)
                      | ((quant_sym(x.z, sc) & 0xff) << 16)
                      | ((quant_sym(x.w, sc) & 0xff) << 24);
        }
    }
    __syncthreads();
    {
        const int dt = tid >> 6, gg = (tid >> 4) & 3;
        const int d = dt * 16 + (tid & 15);
        int4 w = make_int4(Tl[d][gg*4+0], Tl[d][gg*4+1], Tl[d][gg*4+2], Tl[d][gg*4+3]);
        *(int4*)(Vq + (size_t)(bn * 16 + tb) * 1024 + tid * 4) = w;
    }
}

// Phase A: 8 waves/block, wave = 16 s-rows x 128 t's; dq[8] in VGPRs (32 regs).
// Pass 1: integer row-max (monotone). Pass 2: exp2 sum. Cross-wave combine in LDS.
__global__ __launch_bounds__(512) void k_phase_a(const int* __restrict__ Qp,
    const int* __restrict__ Kp, const unsigned* __restrict__ st,
    float* __restrict__ m2_arr, float* __restrict__ l_arr, unsigned* __restrict__ minl)
{
    __shared__ int   Mi[8][16];
    __shared__ float Lf[8][16];
    const int bn = blockIdx.y;
    const int tid = threadIdx.x;
    const int wv = tid >> 6, lane = tid & 63;
    const int g = lane >> 4, c = lane & 15;
    const int s0 = blockIdx.x * 16;
    const float sq = mkscale(st[0], 127.0f);
    const float sk = mkscale(st[1], 127.0f);
    const float cqk2 = (sq * sk * 0.125f) * 1.4426950408889634f;  // log2-domain
    const i32x4_ qf = *(const i32x4_*)(Qp + ((size_t)bn * SS + s0 + c) * 16 + g * 4);
    const i32x4_ zero = {0, 0, 0, 0};
    const int* kb = Kp + ((size_t)bn * SS + wv * 128 + c) * 16 + g * 4;

    i32x4_ dq[8];
    {
        i32x4_ kf = *(const i32x4_*)kb;
        #pragma unroll
        for (int j = 0; j < 8; ++j) {
            i32x4_ kn = (j < 7) ? *(const i32x4_*)(kb + (j + 1) * 256) : kf;
            dq[j] = mfma_i8(kf, qf, zero);   // lane: s = s0+c, t = wv*128 + 16j + 4g + r
            kf = kn;
        }
    }
    int im = -2147483647;
    #pragma unroll
    for (int j = 0; j < 8; ++j) {
        int a01 = max(dq[j][0], dq[j][1]), a23 = max(dq[j][2], dq[j][3]);
        im = max(im, max(a01, a23));
    }
    im = max(im, __shfl_xor(im, 16, 64));
    im = max(im, __shfl_xor(im, 32, 64));
    if (g == 0) Mi[wv][c] = im;
    __syncthreads();
    {
        int m01 = max(Mi[0][c], Mi[1][c]), m23 = max(Mi[2][c], Mi[3][c]);
        int m45 = max(Mi[4][c], Mi[5][c]), m67 = max(Mi[6][c], Mi[7][c]);
        im = max(max(m01, m23), max(m45, m67));
    }
    const float m2 = (float)im * cqk2;    // monotone => equals max of fl(dq*cqk2)
    float la = 0.0f, lb = 0.0f, lc = 0.0f, ld = 0.0f;
    #pragma unroll
    for (int j = 0; j < 8; ++j) {
        la += exp2f(fmaf((float)dq[j][0], cqk2, -m2));
        lb += exp2f(fmaf((float)dq[j][1], cqk2, -m2));
        lc += exp2f(fmaf((float)dq[j][2], cqk2, -m2));
        ld += exp2f(fmaf((float)dq[j][3], cqk2, -m2));
    }
    float l = (la + lb) + (lc + ld);
    l += __shfl_xor(l, 16, 64);
    l += __shfl_xor(l, 32, 64);
    if (g == 0) Lf[wv][c] = l;
    __syncthreads();
    if (tid < 16) {
        const int cc = tid;
        float lr = ((Lf[0][cc] + Lf[1][cc]) + (Lf[2][cc] + Lf[3][cc]))
                 + ((Lf[4][cc] + Lf[5][cc]) + (Lf[6][cc] + Lf[7][cc]));
        m2_arr[bn * SS + s0 + cc] = m2;
        l_arr[bn * SS + s0 + cc] = lr;
        float lm = lr;
        #pragma unroll
        for (int mk = 1; mk <= 8; mk <<= 1) lm = fminf(lm, __shfl_xor(lm, mk, 64));
        if (cc == 0) atomicMin(minl, __float_as_uint(lm));  // l > 0: uint order == float order
    }
}

// Phase B: 8 waves/block = 4 s-groups x 2 t-halves; pipelined QK->quant->LDS transpose->PV.
// Integer acc combine across t-halves in LDS (exact), then coalesced float4 store.
__global__ __launch_bounds__(512) void k_phase_b(const int* __restrict__ Qp,
    const int* __restrict__ Kp, const int* __restrict__ Vq,
    const unsigned* __restrict__ st, const float* __restrict__ m2_arr,
    const float* __restrict__ l_arr, const unsigned* __restrict__ minl,
    float* __restrict__ out)
{
    __shared__ __align__(16) int Pl[8 * 320];    // per-wave 16 x 20-word stride
    __shared__ __align__(16) int sbuf[64 * 65];  // [d][s_local] combine + store staging
    const int bn = blockIdx.y;
    const int tid = threadIdx.x;
    const int wv = tid >> 6, lane = tid & 63;
    const int g = lane >> 4, c = lane & 15;
    const int sgrp = wv & 3, th = wv >> 2;
    const int sblk = blockIdx.x * 64;
    const int s0 = sblk + sgrp * 16;
    const float sq = mkscale(st[0], 127.0f);
    const float sk = mkscale(st[1], 127.0f);
    const float sv = mkscale(st[2], 127.0f);
    const float cqk2 = (sq * sk * 0.125f) * 1.4426950408889634f;
    const float maxP     = 1.0f / __uint_as_float(*minl);
    const float scale_p  = fmaxf(maxP / 255.0f, 1e-8f);
    const float scale_p2 = fmaxf((255.0f * scale_p) / 127.0f, 1e-8f);
    const float cpv = scale_p2 * sv;
    const float C2 = 127.0f / 255.0f;
    const float m2 = m2_arr[bn * SS + s0 + c];
    const float l  = l_arr [bn * SS + s0 + c];
    const float bexp = log2f((1.0f / scale_p) / l) - m2;   // x = exp2(dq*cqk2 + bexp)
    const i32x4_ qf = *(const i32x4_*)(Qp + ((size_t)bn * SS + s0 + c) * 16 + g * 4);
    const i32x4_ zero = {0, 0, 0, 0};
    const int* kbase = Kp + ((size_t)bn * SS + c) * 16 + g * 4;   // + t*16 words
    const int* vbase = Vq + (size_t)bn * 16384 + g * 64 + c * 4;  // + tb*1024 + dt*256
    int* myP = Pl + wv * 320;
    const int woff = c * 20 + g * 4;
    const int tb0 = th * 8;

    i32x4_ acc[4] = {zero, zero, zero, zero};
    i32x4_ vf[4], vn[4];
    #pragma unroll
    for (int dt = 0; dt < 4; ++dt) vf[dt] = *(const i32x4_*)(vbase + tb0 * 1024 + dt * 256);

    int W[4], N[4];
    #pragma unroll
    for (int j = 0; j < 4; ++j) {                       // prologue: W for tb0
        i32x4_ kf = *(const i32x4_*)(kbase + (tb0 * 64 + j * 16) * 16);
        i32x4_ dq = mfma_i8(kf, qf, zero);
        int w = 0;
        #pragma unroll
        for (int r = 0; r < 4; ++r) {
            float x = exp2f(fmaf((float)dq[r], cqk2, bexp));
            float k1 = fminf(rintf(x), 255.0f);          // x >= 0
            int k2 = (int)rintf(k1 * C2);                // <= 127
            w |= k2 << (8 * r);
        }
        W[j] = w;
    }

    for (int i = 0; i < 8; ++i) {
        const int tb = tb0 + i;
        i32x4_ wv4 = {W[0], W[1], W[2], W[3]};
        *(i32x4_*)(myP + woff) = wv4;                    // publish W(tb)
        if (i < 7) {
            const int* vb = vbase + (tb + 1) * 1024;
            #pragma unroll
            for (int dt = 0; dt < 4; ++dt) vn[dt] = *(const i32x4_*)(vb + dt * 256);
            #pragma unroll
            for (int j = 0; j < 4; ++j) {                // QK + quant for tb+1 (hides LDS latency)
                i32x4_ kf = *(const i32x4_*)(kbase + ((tb + 1) * 64 + j * 16) * 16);
                i32x4_ dq = mfma_i8(kf, qf, zero);
                int w = 0;
                #pragma unroll
                for (int r = 0; r < 4; ++r) {
                    float x = exp2f(fmaf((float)dq[r], cqk2, bexp));
                    float k1 = fminf(rintf(x), 255.0f);
                    int k2 = (int)rintf(k1 * C2);
                    w |= k2 << (8 * r);
                }
                N[j] = w;
            }
        }
        i32x4_ pa;                                       // word-transpose read
        pa[0] = myP[c * 20 + 0 + g];
        pa[1] = myP[c * 20 + 4 + g];
        pa[2] = myP[c * 20 + 8 + g];
        pa[3] = myP[c * 20 + 12 + g];
        #pragma unroll
        for (int dt = 0; dt < 4; ++dt) acc[dt] = mfma_i8(pa, vf[dt], acc[dt]);
        #pragma unroll
        for (int dt = 0; dt < 4; ++dt) vf[dt] = vn[dt];
        #pragma unroll
        for (int j = 0; j < 4; ++j) W[j] = N[j];
    }

    // acc lane (c,g) reg (dt,r): d = dt*16 + c, s_local = sgrp*16 + 4g + r
    if (th == 0) {
        #pragma unroll
        for (int dt = 0; dt < 4; ++dt)
            #pragma unroll
            for (int r = 0; r < 4; ++r)
                sbuf[(dt * 16 + c) * 65 + sgrp * 16 + 4 * g + r] = acc[dt][r];
    }
    __syncthreads();
    if (th == 1) {
        #pragma unroll
        for (int dt = 0; dt < 4; ++dt)
            #pragma unroll
            for (int r = 0; r < 4; ++r) {
                const int slot = (dt * 16 + c) * 65 + sgrp * 16 + 4 * g + r;
                ((float*)sbuf)[slot] = (float)(sbuf[slot] + acc[dt][r]) * cpv;
            }
    }
    __syncthreads();
    #pragma unroll
    for (int u = 0; u < 2; ++u) {
        const int chunk = tid + u * 512;         // 0..1023
        const int d = chunk >> 4, sq4 = chunk & 15;
        const float* fb = (const float*)sbuf + d * 65 + sq4 * 4;
        float4 val = make_float4(fb[0], fb[1], fb[2], fb[3]);
        *(float4*)(out + (size_t)bn * 65536 + (size_t)d * 1024 + sblk + sq4 * 4) = val;
    }
}

extern "C" void kernel_launch(void* const* d_in, const int* in_sizes, int n_in,
                              void* d_out, int out_size, void* d_ws, size_t ws_size,
                              hipStream_t stream) {
    const float* q = (const float*)d_in[0];
    const float* k = (const float*)d_in[1];
    const float* v = (const float*)d_in[2];
    float* out = (float*)d_out;
    char* ws = (char*)d_ws;

    unsigned* st = (unsigned*)ws;                                 // [0..2]=amax q,k,v  [3]=min_l
    int* Qp      = (int*)(ws + 1024);                             // 4 MB
    int* Kp      = (int*)(ws + 1024 + (size_t)(1 << 22));         // 4 MB
    int* Vq      = (int*)(ws + 1024 + (size_t)(2 << 22));         // 4 MB (B-fragment order)
    float* m2    = (float*)(ws + 1024 + (size_t)(3 << 22));       // 256 KB
    float* l_a   = (float*)(ws + 1024 + (size_t)(3 << 22) + (1 << 18)); // 256 KB

    k_init<<<1, 64, 0, stream>>>(st);
    k_absmax<<<dim3(256, 3), 256, 0, stream>>>(q, k, v, st);
    k_quant_qk<<<dim3(4, NBN, 2), 256, 0, stream>>>(q, k, st, Qp, Kp);
    k_quant_v<<<dim3(16, NBN), 256, 0, stream>>>(v, st, Vq);
    k_phase_a<<<dim3(64, NBN), 512, 0, stream>>>(Qp, Kp, st, m2, l_a, st + 3);
    k_phase_b<<<dim3(16, NBN), 512, 0, stream>>>(Qp, Kp, Vq, st, m2, l_a, st + 3, out);
}

// Round 5
// 140.846 us; speedup vs baseline: 3.9518x; 1.0064x over previous
//
#include <hip/hip_runtime.h>
#include <math.h>

#define NBN 64      // B*N_HEADS
#define DD  64      // head dim
#define SS  1024    // sequence length (H*W)

typedef int i32x4_ __attribute__((ext_vector_type(4)));

__device__ __forceinline__ i32x4_ mfma_i8(i32x4_ a, i32x4_ b, i32x4_ c) {
    // D[m][n] += sum_k A[m][k]*B[n][k]; A/B lane: m/n = lane&15, k = (lane>>4)*16 + reg*4 + byte
    // C/D: col(n) = lane&15, row(m) = (lane>>4)*4 + reg
    return __builtin_amdgcn_mfma_i32_16x16x64_i8(a, b, c, 0, 0, 0);
}

__device__ __forceinline__ float mkscale(unsigned bits, float qmax) {
    return fmaxf(__uint_as_float(bits) / qmax, 1e-8f);   // jnp.maximum(absmax/qmax, 1e-8)
}

__device__ __forceinline__ int quant_sym(float x, float sc) {
    float r = fminf(fmaxf(rintf(x / sc), -127.0f), 127.0f);  // round-half-even == jnp.round
    return (int)r;
}

__global__ void k_init(unsigned* st) {
    if (threadIdx.x == 0) { st[0]=0u; st[1]=0u; st[2]=0u; st[3]=0x7F800000u; } // minl = +inf
}

__global__ void k_absmax(const float* __restrict__ q, const float* __restrict__ k,
                         const float* __restrict__ v, unsigned* __restrict__ st) {
    const float* src = (blockIdx.y == 0) ? q : (blockIdx.y == 1) ? k : v;
    const int n = NBN * DD * SS;
    float m = 0.0f;
    for (int i = (blockIdx.x * 256 + threadIdx.x) * 4; i < n; i += gridDim.x * 256 * 4) {
        float4 x = *(const float4*)(src + i);
        m = fmaxf(m, fmaxf(fmaxf(fabsf(x.x), fabsf(x.y)), fmaxf(fabsf(x.z), fabsf(x.w))));
    }
    __shared__ float red[256];
    red[threadIdx.x] = m;
    __syncthreads();
    for (int off = 128; off > 0; off >>= 1) {
        if (threadIdx.x < off) red[threadIdx.x] = fmaxf(red[threadIdx.x], red[threadIdx.x + off]);
        __syncthreads();
    }
    if (threadIdx.x == 0) atomicMax(st + blockIdx.y, __float_as_uint(red[0]));
}

// Q,K: quantize + transpose-pack: Qp[bn][s][j] = pack_i8(iq[4j..4j+3][s]), j=0..15
__global__ void k_quant_qk(const float* __restrict__ q, const float* __restrict__ k,
                           const unsigned* __restrict__ st,
                           int* __restrict__ Qp, int* __restrict__ Kp) {
    const int which = blockIdx.z;
    const float* src = which ? k : q;
    int* dst = which ? Kp : Qp;
    const float sc = mkscale(st[which], 127.0f);
    const int bn = blockIdx.y;
    const int s = blockIdx.x * 256 + threadIdx.x;
    const float* tsrc = src + (size_t)bn * DD * SS;
    int4* tdst4 = (int4*)(dst + ((size_t)bn * SS + s) * 16);
    #pragma unroll
    for (int jj = 0; jj < 4; ++jj) {
        int pw[4];
        #pragma unroll
        for (int u = 0; u < 4; ++u) {
            const int j = jj * 4 + u;
            int p = 0;
            #pragma unroll
            for (int r = 0; r < 4; ++r) {
                int iq = quant_sym(tsrc[(size_t)(4 * j + r) * SS + s], sc);
                p |= (iq & 0xff) << (8 * r);
            }
            pw[u] = p;
        }
        tdst4[jj] = make_int4(pw[0], pw[1], pw[2], pw[3]);
    }
}

// V: quantize + pack into PV B-fragment order.
__global__ void k_quant_v(const float* __restrict__ v, const unsigned* __restrict__ st,
                          int* __restrict__ Vq) {
    __shared__ __align__(16) int Tl[64][20];
    const float sc = mkscale(st[2], 127.0f);
    const int bn = blockIdx.y, tb = blockIdx.x;
    const int tid = threadIdx.x;
    {
        const int d = tid >> 2, tqq = tid & 3;
        #pragma unroll
        for (int i = 0; i < 4; ++i) {
            const int tq = tqq * 4 + i;
            float4 x = *(const float4*)(v + (size_t)(bn * 64 + d) * SS + tb * 64 + tq * 4);
            Tl[d][tq] = (quant_sym(x.x, sc) & 0xff)
                      | ((quant_sym(x.y, sc) & 0xff) << 8)
                      | ((quant_sym(x.z, sc) & 0xff) << 16)
                      | ((quant_sym(x.w, sc) & 0xff) << 24);
        }
    }
    __syncthreads();
    {
        const int dt = tid >> 6, gg = (tid >> 4) & 3;
        const int d = dt * 16 + (tid & 15);
        int4 w = make_int4(Tl[d][gg*4+0], Tl[d][gg*4+1], Tl[d][gg*4+2], Tl[d][gg*4+3]);
        *(int4*)(Vq + (size_t)(bn * 16 + tb) * 1024 + tid * 4) = w;
    }
}

// Phase A: 8 waves/block, wave = 16 s-rows x 128 t's.
// K fragments batch-preloaded into registers (8 loads in flight), then 8 MFMAs.
// Pass 1: integer row-max (monotone). Pass 2: exp2 sum. Cross-wave combine in LDS.
// XCD swizzle: flat block id f -> bn = ((f&7)<<3)|((f>>3)&7) so each XCD's L2 owns 8 bn slabs.
__global__ __launch_bounds__(512) void k_phase_a(const int* __restrict__ Qp,
    const int* __restrict__ Kp, const unsigned* __restrict__ st,
    float* __restrict__ m2_arr, float* __restrict__ l_arr, unsigned* __restrict__ minl)
{
    __shared__ int   Mi[8][16];
    __shared__ float Lf[8][16];
    const int f = blockIdx.x + (blockIdx.y << 6);          // grid (64,64) flat
    const int bn = ((f & 7) << 3) | ((f >> 3) & 7);
    const int s0 = (f >> 6) * 16;
    const int tid = threadIdx.x;
    const int wv = tid >> 6, lane = tid & 63;
    const int g = lane >> 4, c = lane & 15;
    const float sq = mkscale(st[0], 127.0f);
    const float sk = mkscale(st[1], 127.0f);
    const float cqk2 = (sq * sk * 0.125f) * 1.4426950408889634f;  // log2-domain
    const i32x4_ qf = *(const i32x4_*)(Qp + ((size_t)bn * SS + s0 + c) * 16 + g * 4);
    const i32x4_ zero = {0, 0, 0, 0};
    const int* kb = Kp + ((size_t)bn * SS + wv * 128 + c) * 16 + g * 4;

    i32x4_ kfr[8];
    #pragma unroll
    for (int j = 0; j < 8; ++j) kfr[j] = *(const i32x4_*)(kb + j * 256);  // all loads in flight
    i32x4_ dq[8];
    #pragma unroll
    for (int j = 0; j < 8; ++j) dq[j] = mfma_i8(kfr[j], qf, zero);  // s = s0+c, t = wv*128+16j+4g+r

    int im = -2147483647;
    #pragma unroll
    for (int j = 0; j < 8; ++j) {
        int a01 = max(dq[j][0], dq[j][1]), a23 = max(dq[j][2], dq[j][3]);
        im = max(im, max(a01, a23));
    }
    im = max(im, __shfl_xor(im, 16, 64));
    im = max(im, __shfl_xor(im, 32, 64));
    if (g == 0) Mi[wv][c] = im;
    __syncthreads();
    {
        int m01 = max(Mi[0][c], Mi[1][c]), m23 = max(Mi[2][c], Mi[3][c]);
        int m45 = max(Mi[4][c], Mi[5][c]), m67 = max(Mi[6][c], Mi[7][c]);
        im = max(max(m01, m23), max(m45, m67));
    }
    const float m2 = (float)im * cqk2;    // monotone => equals max of fl(dq*cqk2)
    float la = 0.0f, lb = 0.0f, lc = 0.0f, ld = 0.0f;
    #pragma unroll
    for (int j = 0; j < 8; ++j) {
        la += exp2f(fmaf((float)dq[j][0], cqk2, -m2));
        lb += exp2f(fmaf((float)dq[j][1], cqk2, -m2));
        lc += exp2f(fmaf((float)dq[j][2], cqk2, -m2));
        ld += exp2f(fmaf((float)dq[j][3], cqk2, -m2));
    }
    float l = (la + lb) + (lc + ld);
    l += __shfl_xor(l, 16, 64);
    l += __shfl_xor(l, 32, 64);
    if (g == 0) Lf[wv][c] = l;
    __syncthreads();
    if (tid < 16) {
        const int cc = tid;
        float lr = ((Lf[0][cc] + Lf[1][cc]) + (Lf[2][cc] + Lf[3][cc]))
                 + ((Lf[4][cc] + Lf[5][cc]) + (Lf[6][cc] + Lf[7][cc]));
        m2_arr[bn * SS + s0 + cc] = m2;
        l_arr[bn * SS + s0 + cc] = lr;
        float lm = lr;
        #pragma unroll
        for (int mk = 1; mk <= 8; mk <<= 1) lm = fminf(lm, __shfl_xor(lm, mk, 64));
        if (cc == 0) atomicMin(minl, __float_as_uint(lm));  // l > 0: uint order == float order
    }
}

// Phase B: 8 waves/block = 4 s-groups x 2 t-halves; batch-prefetched K+V (8 loads in flight
// per iteration, issued before the compute that hides them). Integer acc combine across
// t-halves in LDS (exact), then coalesced float4 store. Same XCD swizzle as phase A.
__global__ __launch_bounds__(512) void k_phase_b(const int* __restrict__ Qp,
    const int* __restrict__ Kp, const int* __restrict__ Vq,
    const unsigned* __restrict__ st, const float* __restrict__ m2_arr,
    const float* __restrict__ l_arr, const unsigned* __restrict__ minl,
    float* __restrict__ out)
{
    __shared__ __align__(16) int Pl[8 * 320];    // per-wave 16 x 20-word stride
    __shared__ __align__(16) int sbuf[64 * 65];  // [d][s_local] combine + store staging
    const int f = blockIdx.x + (blockIdx.y << 4);          // grid (16,64) flat
    const int bn = ((f & 7) << 3) | ((f >> 3) & 7);
    const int sblk = (f >> 6) * 64;
    const int tid = threadIdx.x;
    const int wv = tid >> 6, lane = tid & 63;
    const int g = lane >> 4, c = lane & 15;
    const int sgrp = wv & 3, th = wv >> 2;
    const int s0 = sblk + sgrp * 16;
    const float sq = mkscale(st[0], 127.0f);
    const float sk = mkscale(st[1], 127.0f);
    const float sv = mkscale(st[2], 127.0f);
    const float cqk2 = (sq * sk * 0.125f) * 1.4426950408889634f;
    const float maxP     = 1.0f / __uint_as_float(*minl);
    const float scale_p  = fmaxf(maxP / 255.0f, 1e-8f);
    const float scale_p2 = fmaxf((255.0f * scale_p) / 127.0f, 1e-8f);
    const float cpv = scale_p2 * sv;
    const float C2 = 127.0f / 255.0f;
    const float m2 = m2_arr[bn * SS + s0 + c];
    const float l  = l_arr [bn * SS + s0 + c];
    const float bexp = log2f((1.0f / scale_p) / l) - m2;   // x = exp2(dq*cqk2 + bexp)
    const i32x4_ qf = *(const i32x4_*)(Qp + ((size_t)bn * SS + s0 + c) * 16 + g * 4);
    const i32x4_ zero = {0, 0, 0, 0};
    const int* kbase = Kp + ((size_t)bn * SS + c) * 16 + g * 4;   // + t*16 words
    const int* vbase = Vq + (size_t)bn * 16384 + g * 64 + c * 4;  // + tb*1024 + dt*256
    int* myP = Pl + wv * 320;
    const int woff = c * 20 + g * 4;
    const int tb0 = th * 8;

    i32x4_ acc[4] = {zero, zero, zero, zero};
    i32x4_ kf[4], kn[4], vf[4], vn[4];
    #pragma unroll
    for (int j = 0; j < 4; ++j) kf[j] = *(const i32x4_*)(kbase + (tb0 * 64 + j * 16) * 16);
    #pragma unroll
    for (int dt = 0; dt < 4; ++dt) vf[dt] = *(const i32x4_*)(vbase + tb0 * 1024 + dt * 256);

    #pragma unroll
    for (int i = 0; i < 8; ++i) {
        const int tb = tb0 + i;
        if (i < 7) {                                     // issue next-iter loads first (8 in flight)
            #pragma unroll
            for (int j = 0; j < 4; ++j) kn[j] = *(const i32x4_*)(kbase + ((tb + 1) * 64 + j * 16) * 16);
            #pragma unroll
            for (int dt = 0; dt < 4; ++dt) vn[dt] = *(const i32x4_*)(vbase + (tb + 1) * 1024 + dt * 256);
        }
        int W[4];
        #pragma unroll
        for (int j = 0; j < 4; ++j) {                    // QK + quantize P (hides the loads)
            i32x4_ dq = mfma_i8(kf[j], qf, zero);
            int w = 0;
            #pragma unroll
            for (int r = 0; r < 4; ++r) {
                float x = exp2f(fmaf((float)dq[r], cqk2, bexp));
                float k1 = fminf(rintf(x), 255.0f);      // x >= 0
                int k2 = (int)rintf(k1 * C2);            // <= 127
                w |= k2 << (8 * r);
            }
            W[j] = w;
        }
        i32x4_ wv4 = {W[0], W[1], W[2], W[3]};
        *(i32x4_*)(myP + woff) = wv4;                    // publish W(tb)
        i32x4_ pa;                                       // word-transpose read
        pa[0] = myP[c * 20 + 0 + g];
        pa[1] = myP[c * 20 + 4 + g];
        pa[2] = myP[c * 20 + 8 + g];
        pa[3] = myP[c * 20 + 12 + g];
        #pragma unroll
        for (int dt = 0; dt < 4; ++dt) acc[dt] = mfma_i8(pa, vf[dt], acc[dt]);
        #pragma unroll
        for (int j = 0; j < 4; ++j) kf[j] = kn[j];
        #pragma unroll
        for (int dt = 0; dt < 4; ++dt) vf[dt] = vn[dt];
    }

    // acc lane (c,g) reg (dt,r): d = dt*16 + c, s_local = sgrp*16 + 4g + r
    if (th == 0) {
        #pragma unroll
        for (int dt = 0; dt < 4; ++dt)
            #pragma unroll
            for (int r = 0; r < 4; ++r)
                sbuf[(dt * 16 + c) * 65 + sgrp * 16 + 4 * g + r] = acc[dt][r];
    }
    __syncthreads();
    if (th == 1) {
        #pragma unroll
        for (int dt = 0; dt < 4; ++dt)
            #pragma unroll
            for (int r = 0; r < 4; ++r) {
                const int slot = (dt * 16 + c) * 65 + sgrp * 16 + 4 * g + r;
                ((float*)sbuf)[slot] = (float)(sbuf[slot] + acc[dt][r]) * cpv;
            }
    }
    __syncthreads();
    #pragma unroll
    for (int u = 0; u < 2; ++u) {
        const int chunk = tid + u * 512;         // 0..1023
        const int d = chunk >> 4, sq4 = chunk & 15;
        const float* fb = (const float*)sbuf + d * 65 + sq4 * 4;
        float4 val = make_float4(fb[0], fb[1], fb[2], fb[3]);
        *(float4*)(out + (size_t)bn * 65536 + (size_t)d * 1024 + sblk + sq4 * 4) = val;
    }
}

extern "C" void kernel_launch(void* const* d_in, const int* in_sizes, int n_in,
                              void* d_out, int out_size, void* d_ws, size_t ws_size,
                              hipStream_t stream) {
    const float* q = (const float*)d_in[0];
    const float* k = (const float*)d_in[1];
    const float* v = (const float*)d_in[2];
    float* out = (float*)d_out;
    char* ws = (char*)d_ws;

    unsigned* st = (unsigned*)ws;                                 // [0..2]=amax q,k,v  [3]=min_l
    int* Qp      = (int*)(ws + 1024);                             // 4 MB
    int* Kp      = (int*)(ws + 1024 + (size_t)(1 << 22));         // 4 MB
    int* Vq      = (int*)(ws + 1024 + (size_t)(2 << 22));         // 4 MB (B-fragment order)
    float* m2    = (float*)(ws + 1024 + (size_t)(3 << 22));       // 256 KB
    float* l_a   = (float*)(ws + 1024 + (size_t)(3 << 22) + (1 << 18)); // 256 KB

    k_init<<<1, 64, 0, stream>>>(st);
    k_absmax<<<dim3(256, 3), 256, 0, stream>>>(q, k, v, st);
    k_quant_qk<<<dim3(4, NBN, 2), 256, 0, stream>>>(q, k, st, Qp, Kp);
    k_quant_v<<<dim3(16, NBN), 256, 0, stream>>>(v, st, Vq);
    k_phase_a<<<dim3(64, NBN), 512, 0, stream>>>(Qp, Kp, st, m2, l_a, st + 3);
    k_phase_b<<<dim3(16, NBN), 512, 0, stream>>>(Qp, Kp, Vq, st, m2, l_a, st + 3, out);
}

// Round 6
// 120.409 us; speedup vs baseline: 4.6225x; 1.1697x over previous
//
#include <hip/hip_runtime.h>
#include <math.h>

#define NBN 64      // B*N_HEADS
#define DD  64      // head dim
#define SS  1024    // sequence length (H*W)

typedef int i32x4_ __attribute__((ext_vector_type(4)));

__device__ __forceinline__ i32x4_ mfma_i8(i32x4_ a, i32x4_ b, i32x4_ c) {
    // D[m][n] += sum_k A[m][k]*B[n][k]; A/B lane: m/n = lane&15, k = (lane>>4)*16 + reg*4 + byte
    // C/D: col(n) = lane&15, row(m) = (lane>>4)*4 + reg
    return __builtin_amdgcn_mfma_i32_16x16x64_i8(a, b, c, 0, 0, 0);
}

__device__ __forceinline__ float mkscale(unsigned bits, float qmax) {
    return fmaxf(__uint_as_float(bits) / qmax, 1e-8f);   // jnp.maximum(absmax/qmax, 1e-8)
}

__device__ __forceinline__ int quant_sym(float x, float sc) {
    float r = fminf(fmaxf(rintf(x / sc), -127.0f), 127.0f);  // round-half-even == jnp.round
    return (int)r;
}

__global__ void k_init(unsigned* st) {
    if (threadIdx.x == 0) { st[0]=0u; st[1]=0u; st[2]=0u; st[3]=0x7F800000u; } // minl = +inf
}

__global__ void k_absmax(const float* __restrict__ q, const float* __restrict__ k,
                         const float* __restrict__ v, unsigned* __restrict__ st) {
    const float* src = (blockIdx.y == 0) ? q : (blockIdx.y == 1) ? k : v;
    const int n = NBN * DD * SS;
    float m = 0.0f;
    for (int i = (blockIdx.x * 256 + threadIdx.x) * 4; i < n; i += gridDim.x * 256 * 4) {
        float4 x = *(const float4*)(src + i);
        m = fmaxf(m, fmaxf(fmaxf(fabsf(x.x), fabsf(x.y)), fmaxf(fabsf(x.z), fabsf(x.w))));
    }
    __shared__ float red[256];
    red[threadIdx.x] = m;
    __syncthreads();
    for (int off = 128; off > 0; off >>= 1) {
        if (threadIdx.x < off) red[threadIdx.x] = fmaxf(red[threadIdx.x], red[threadIdx.x + off]);
        __syncthreads();
    }
    if (threadIdx.x == 0) atomicMax(st + blockIdx.y, __float_as_uint(red[0]));
}

// Q,K: quantize + transpose-pack: Qp[bn][s][j] = pack_i8(iq[4j..4j+3][s]), j=0..15
__global__ void k_quant_qk(const float* __restrict__ q, const float* __restrict__ k,
                           const unsigned* __restrict__ st,
                           int* __restrict__ Qp, int* __restrict__ Kp) {
    const int which = blockIdx.z;
    const float* src = which ? k : q;
    int* dst = which ? Kp : Qp;
    const float sc = mkscale(st[which], 127.0f);
    const int bn = blockIdx.y;
    const int s = blockIdx.x * 256 + threadIdx.x;
    const float* tsrc = src + (size_t)bn * DD * SS;
    int4* tdst4 = (int4*)(dst + ((size_t)bn * SS + s) * 16);
    #pragma unroll
    for (int jj = 0; jj < 4; ++jj) {
        int pw[4];
        #pragma unroll
        for (int u = 0; u < 4; ++u) {
            const int j = jj * 4 + u;
            int p = 0;
            #pragma unroll
            for (int r = 0; r < 4; ++r) {
                int iq = quant_sym(tsrc[(size_t)(4 * j + r) * SS + s], sc);
                p |= (iq & 0xff) << (8 * r);
            }
            pw[u] = p;
        }
        tdst4[jj] = make_int4(pw[0], pw[1], pw[2], pw[3]);
    }
}

// V: quantize + pack into PV B-fragment order.
__global__ void k_quant_v(const float* __restrict__ v, const unsigned* __restrict__ st,
                          int* __restrict__ Vq) {
    __shared__ __align__(16) int Tl[64][20];
    const float sc = mkscale(st[2], 127.0f);
    const int bn = blockIdx.y, tb = blockIdx.x;
    const int tid = threadIdx.x;
    {
        const int d = tid >> 2, tqq = tid & 3;
        #pragma unroll
        for (int i = 0; i < 4; ++i) {
            const int tq = tqq * 4 + i;
            float4 x = *(const float4*)(v + (size_t)(bn * 64 + d) * SS + tb * 64 + tq * 4);
            Tl[d][tq] = (quant_sym(x.x, sc) & 0xff)
                      | ((quant_sym(x.y, sc) & 0xff) << 8)
                      | ((quant_sym(x.z, sc) & 0xff) << 16)
                      | ((quant_sym(x.w, sc) & 0xff) << 24);
        }
    }
    __syncthreads();
    {
        const int dt = tid >> 6, gg = (tid >> 4) & 3;
        const int d = dt * 16 + (tid & 15);
        int4 w = make_int4(Tl[d][gg*4+0], Tl[d][gg*4+1], Tl[d][gg*4+2], Tl[d][gg*4+3]);
        *(int4*)(Vq + (size_t)(bn * 16 + tb) * 1024 + tid * 4) = w;
    }
}

// Phase A: 8 waves/block; wave = 32 s-rows (2 tiles) x 128 t's off the SAME 8 K-fragments.
// sched_barrier pins all 8 K loads in flight before any MFMA (defeats compiler re-sinking).
// Pass 1: integer row-max (monotone). Pass 2: exp2 sum. Cross-wave combine in LDS.
// XCD swizzle: bn = ((x&7)<<3)|((x>>3)&7) so each XCD's L2 owns 8 bn slabs.
__global__ __launch_bounds__(512) void k_phase_a(const int* __restrict__ Qp,
    const int* __restrict__ Kp, const unsigned* __restrict__ st,
    float* __restrict__ m2_arr, float* __restrict__ l_arr, unsigned* __restrict__ minl)
{
    __shared__ int   Mi[8][32];
    __shared__ float Lf[8][32];
    const int x = blockIdx.x;                              // 0..63 -> bn (swizzled)
    const int bn = ((x & 7) << 3) | ((x >> 3) & 7);
    const int s0 = blockIdx.y * 32;                        // 0..31 -> s pair-tile
    const int tid = threadIdx.x;
    const int wv = tid >> 6, lane = tid & 63;
    const int g = lane >> 4, c = lane & 15;
    const float sq = mkscale(st[0], 127.0f);
    const float sk = mkscale(st[1], 127.0f);
    const float cqk2 = (sq * sk * 0.125f) * 1.4426950408889634f;  // log2-domain
    const i32x4_ qf0 = *(const i32x4_*)(Qp + ((size_t)bn * SS + s0 + c) * 16 + g * 4);
    const i32x4_ qf1 = *(const i32x4_*)(Qp + ((size_t)bn * SS + s0 + 16 + c) * 16 + g * 4);
    const i32x4_ zero = {0, 0, 0, 0};
    const int* kb = Kp + ((size_t)bn * SS + wv * 128 + c) * 16 + g * 4;

    i32x4_ kfr[8];
    #pragma unroll
    for (int j = 0; j < 8; ++j) kfr[j] = *(const i32x4_*)(kb + j * 256);
    __builtin_amdgcn_sched_barrier(0);                     // all 8 loads issued before compute
    i32x4_ dq0[8], dq1[8];
    #pragma unroll
    for (int j = 0; j < 8; ++j) {
        dq0[j] = mfma_i8(kfr[j], qf0, zero);   // s = s0+c,    t = wv*128+16j+4g+r
        dq1[j] = mfma_i8(kfr[j], qf1, zero);   // s = s0+16+c, same t
    }

    int im0 = -2147483647, im1 = -2147483647;
    #pragma unroll
    for (int j = 0; j < 8; ++j) {
        im0 = max(im0, max(max(dq0[j][0], dq0[j][1]), max(dq0[j][2], dq0[j][3])));
        im1 = max(im1, max(max(dq1[j][0], dq1[j][1]), max(dq1[j][2], dq1[j][3])));
    }
    im0 = max(im0, __shfl_xor(im0, 16, 64));
    im0 = max(im0, __shfl_xor(im0, 32, 64));
    im1 = max(im1, __shfl_xor(im1, 16, 64));
    im1 = max(im1, __shfl_xor(im1, 32, 64));
    if (g == 0) { Mi[wv][c] = im0; Mi[wv][16 + c] = im1; }
    __syncthreads();
    {
        int a0 = Mi[0][c], a1 = Mi[0][16 + c];
        #pragma unroll
        for (int w = 1; w < 8; ++w) { a0 = max(a0, Mi[w][c]); a1 = max(a1, Mi[w][16 + c]); }
        im0 = a0; im1 = a1;
    }
    const float m20 = (float)im0 * cqk2;   // monotone => equals max of fl(dq*cqk2)
    const float m21 = (float)im1 * cqk2;
    float la0 = 0.0f, lb0 = 0.0f, lc0 = 0.0f, ld0 = 0.0f;
    float la1 = 0.0f, lb1 = 0.0f, lc1 = 0.0f, ld1 = 0.0f;
    #pragma unroll
    for (int j = 0; j < 8; ++j) {
        la0 += exp2f(fmaf((float)dq0[j][0], cqk2, -m20));
        lb0 += exp2f(fmaf((float)dq0[j][1], cqk2, -m20));
        lc0 += exp2f(fmaf((float)dq0[j][2], cqk2, -m20));
        ld0 += exp2f(fmaf((float)dq0[j][3], cqk2, -m20));
        la1 += exp2f(fmaf((float)dq1[j][0], cqk2, -m21));
        lb1 += exp2f(fmaf((float)dq1[j][1], cqk2, -m21));
        lc1 += exp2f(fmaf((float)dq1[j][2], cqk2, -m21));
        ld1 += exp2f(fmaf((float)dq1[j][3], cqk2, -m21));
    }
    float l0 = (la0 + lb0) + (lc0 + ld0);
    float l1 = (la1 + lb1) + (lc1 + ld1);
    l0 += __shfl_xor(l0, 16, 64);
    l0 += __shfl_xor(l0, 32, 64);
    l1 += __shfl_xor(l1, 16, 64);
    l1 += __shfl_xor(l1, 32, 64);
    if (g == 0) { Lf[wv][c] = l0; Lf[wv][16 + c] = l1; }
    __syncthreads();
    if (tid < 32) {
        const int cc = tid;
        float lr = ((Lf[0][cc] + Lf[1][cc]) + (Lf[2][cc] + Lf[3][cc]))
                 + ((Lf[4][cc] + Lf[5][cc]) + (Lf[6][cc] + Lf[7][cc]));
        int imr = Mi[0][cc];
        #pragma unroll
        for (int w = 1; w < 8; ++w) imr = max(imr, Mi[w][cc]);
        m2_arr[bn * SS + s0 + cc] = (float)imr * cqk2;
        l_arr[bn * SS + s0 + cc] = lr;
        float lm = lr;
        #pragma unroll
        for (int mk = 1; mk <= 16; mk <<= 1) lm = fminf(lm, __shfl_xor(lm, mk, 64));
        if (cc == 0) atomicMin(minl, __float_as_uint(lm));  // l > 0: uint order == float order
    }
}

// Phase B: 8 waves/block = 4 s-groups x 2 t-halves; prefetch batch pinned ahead of compute
// by sched_barrier; fully unrolled i-loop keeps kf/kn as SSA (no copy-induced waits).
// Integer acc combine across t-halves in LDS (exact), then coalesced float4 store.
__global__ __launch_bounds__(512) void k_phase_b(const int* __restrict__ Qp,
    const int* __restrict__ Kp, const int* __restrict__ Vq,
    const unsigned* __restrict__ st, const float* __restrict__ m2_arr,
    const float* __restrict__ l_arr, const unsigned* __restrict__ minl,
    float* __restrict__ out)
{
    __shared__ __align__(16) int Pl[8 * 320];    // per-wave 16 x 20-word stride
    __shared__ __align__(16) int sbuf[64 * 65];  // [d][s_local] combine + store staging
    const int f = blockIdx.x + (blockIdx.y << 4);          // grid (16,64) flat
    const int bn = ((f & 7) << 3) | ((f >> 3) & 7);
    const int sblk = (f >> 6) * 64;
    const int tid = threadIdx.x;
    const int wv = tid >> 6, lane = tid & 63;
    const int g = lane >> 4, c = lane & 15;
    const int sgrp = wv & 3, th = wv >> 2;
    const int s0 = sblk + sgrp * 16;
    const float sq = mkscale(st[0], 127.0f);
    const float sk = mkscale(st[1], 127.0f);
    const float sv = mkscale(st[2], 127.0f);
    const float cqk2 = (sq * sk * 0.125f) * 1.4426950408889634f;
    const float maxP     = 1.0f / __uint_as_float(*minl);
    const float scale_p  = fmaxf(maxP / 255.0f, 1e-8f);
    const float scale_p2 = fmaxf((255.0f * scale_p) / 127.0f, 1e-8f);
    const float cpv = scale_p2 * sv;
    const float C2 = 127.0f / 255.0f;
    const float m2 = m2_arr[bn * SS + s0 + c];
    const float l  = l_arr [bn * SS + s0 + c];
    const float bexp = log2f((1.0f / scale_p) / l) - m2;   // x = exp2(dq*cqk2 + bexp)
    const i32x4_ qf = *(const i32x4_*)(Qp + ((size_t)bn * SS + s0 + c) * 16 + g * 4);
    const i32x4_ zero = {0, 0, 0, 0};
    const int* kbase = Kp + ((size_t)bn * SS + c) * 16 + g * 4;   // + t*16 words
    const int* vbase = Vq + (size_t)bn * 16384 + g * 64 + c * 4;  // + tb*1024 + dt*256
    int* myP = Pl + wv * 320;
    const int woff = c * 20 + g * 4;
    const int tb0 = th * 8;

    i32x4_ acc[4] = {zero, zero, zero, zero};
    i32x4_ kf[4], kn[4], vf[4], vn[4];
    #pragma unroll
    for (int j = 0; j < 4; ++j) kf[j] = *(const i32x4_*)(kbase + (tb0 * 64 + j * 16) * 16);
    #pragma unroll
    for (int dt = 0; dt < 4; ++dt) vf[dt] = *(const i32x4_*)(vbase + tb0 * 1024 + dt * 256);

    #pragma unroll
    for (int i = 0; i < 8; ++i) {
        const int tb = tb0 + i;
        if (i < 7) {                                     // issue next-iter loads (8 in flight)
            #pragma unroll
            for (int j = 0; j < 4; ++j) kn[j] = *(const i32x4_*)(kbase + ((tb + 1) * 64 + j * 16) * 16);
            #pragma unroll
            for (int dt = 0; dt < 4; ++dt) vn[dt] = *(const i32x4_*)(vbase + (tb + 1) * 1024 + dt * 256);
        }
        __builtin_amdgcn_sched_barrier(0);               // loads stay above the compute
        int W[4];
        #pragma unroll
        for (int j = 0; j < 4; ++j) {                    // QK + quantize P (hides the loads)
            i32x4_ dq = mfma_i8(kf[j], qf, zero);
            int w = 0;
            #pragma unroll
            for (int r = 0; r < 4; ++r) {
                float x = exp2f(fmaf((float)dq[r], cqk2, bexp));
                float k1 = fminf(rintf(x), 255.0f);      // x >= 0
                int k2 = (int)rintf(k1 * C2);            // <= 127
                w |= k2 << (8 * r);
            }
            W[j] = w;
        }
        i32x4_ wv4 = {W[0], W[1], W[2], W[3]};
        *(i32x4_*)(myP + woff) = wv4;                    // publish W(tb)
        i32x4_ pa;                                       // word-transpose read
        pa[0] = myP[c * 20 + 0 + g];
        pa[1] = myP[c * 20 + 4 + g];
        pa[2] = myP[c * 20 + 8 + g];
        pa[3] = myP[c * 20 + 12 + g];
        #pragma unroll
        for (int dt = 0; dt < 4; ++dt) acc[dt] = mfma_i8(pa, vf[dt], acc[dt]);
        #pragma unroll
        for (int j = 0; j < 4; ++j) kf[j] = kn[j];
        #pragma unroll
        for (int dt = 0; dt < 4; ++dt) vf[dt] = vn[dt];
    }

    // acc lane (c,g) reg (dt,r): d = dt*16 + c, s_local = sgrp*16 + 4g + r
    if (th == 0) {
        #pragma unroll
        for (int dt = 0; dt < 4; ++dt)
            #pragma unroll
            for (int r = 0; r < 4; ++r)
                sbuf[(dt * 16 + c) * 65 + sgrp * 16 + 4 * g + r] = acc[dt][r];
    }
    __syncthreads();
    if (th == 1) {
        #pragma unroll
        for (int dt = 0; dt < 4; ++dt)
            #pragma unroll
            for (int r = 0; r < 4; ++r) {
                const int slot = (dt * 16 + c) * 65 + sgrp * 16 + 4 * g + r;
                ((float*)sbuf)[slot] = (float)(sbuf[slot] + acc[dt][r]) * cpv;
            }
    }
    __syncthreads();
    #pragma unroll
    for (int u = 0; u < 2; ++u) {
        const int chunk = tid + u * 512;         // 0..1023
        const int d = chunk >> 4, sq4 = chunk & 15;
        const float* fb = (const float*)sbuf + d * 65 + sq4 * 4;
        float4 val = make_float4(fb[0], fb[1], fb[2], fb[3]);
        *(float4*)(out + (size_t)bn * 65536 + (size_t)d * 1024 + sblk + sq4 * 4) = val;
    }
}

extern "C" void kernel_launch(void* const* d_in, const int* in_sizes, int n_in,
                              void* d_out, int out_size, void* d_ws, size_t ws_size,
                              hipStream_t stream) {
    const float* q = (const float*)d_in[0];
    const float* k = (const float*)d_in[1];
    const float* v = (const float*)d_in[2];
    float* out = (float*)d_out;
    char* ws = (char*)d_ws;

    unsigned* st = (unsigned*)ws;                                 // [0..2]=amax q,k,v  [3]=min_l
    int* Qp      = (int*)(ws + 1024);                             // 4 MB
    int* Kp      = (int*)(ws + 1024 + (size_t)(1 << 22));         // 4 MB
    int* Vq      = (int*)(ws + 1024 + (size_t)(2 << 22));         // 4 MB (B-fragment order)
    float* m2    = (float*)(ws + 1024 + (size_t)(3 << 22));       // 256 KB
    float* l_a   = (float*)(ws + 1024 + (size_t)(3 << 22) + (1 << 18)); // 256 KB

    k_init<<<1, 64, 0, stream>>>(st);
    k_absmax<<<dim3(256, 3), 256, 0, stream>>>(q, k, v, st);
    k_quant_qk<<<dim3(4, NBN, 2), 256, 0, stream>>>(q, k, st, Qp, Kp);
    k_quant_v<<<dim3(16, NBN), 256, 0, stream>>>(v, st, Vq);
    k_phase_a<<<dim3(64, 32), 512, 0, stream>>>(Qp, Kp, st, m2, l_a, st + 3);
    k_phase_b<<<dim3(16, NBN), 512, 0, stream>>>(Qp, Kp, Vq, st, m2, l_a, st + 3, out);
}

// Round 7
// 92.628 us; speedup vs baseline: 6.0089x; 1.2999x over previous
//
#include <hip/hip_runtime.h>
#include <math.h>

#define NBN 64      // B*N_HEADS
#define DD  64      // head dim
#define SS  1024    // sequence length (H*W)

typedef int i32x4_ __attribute__((ext_vector_type(4)));

// raw v_exp_f32 (no OCML denormal wrapper). Args here are always well in range.
#if defined(__has_builtin)
#  if __has_builtin(__builtin_amdgcn_exp2f)
#    define FEXP2(x) __builtin_amdgcn_exp2f(x)
#  endif
#endif
#ifndef FEXP2
#  define FEXP2(x) exp2f(x)
#endif

__device__ __forceinline__ i32x4_ mfma_i8(i32x4_ a, i32x4_ b, i32x4_ c) {
    // D[m][n] += sum_k A[m][k]*B[n][k]; A/B lane: m/n = lane&15, k = (lane>>4)*16 + reg*4 + byte
    // C/D: col(n) = lane&15, row(m) = (lane>>4)*4 + reg
    return __builtin_amdgcn_mfma_i32_16x16x64_i8(a, b, c, 0, 0, 0);
}

__device__ __forceinline__ float mkscale(unsigned bits, float qmax) {
    return fmaxf(__uint_as_float(bits) / qmax, 1e-8f);   // jnp.maximum(absmax/qmax, 1e-8)
}

__device__ __forceinline__ int quant_sym(float x, float sc) {
    float r = fminf(fmaxf(rintf(x / sc), -127.0f), 127.0f);  // round-half-even == jnp.round
    return (int)r;
}

__global__ void k_init(unsigned* st) {
    if (threadIdx.x == 0) { st[0]=0u; st[1]=0u; st[2]=0u; st[3]=0x7F800000u; } // minl = +inf
}

__global__ void k_absmax(const float* __restrict__ q, const float* __restrict__ k,
                         const float* __restrict__ v, unsigned* __restrict__ st) {
    const float* src = (blockIdx.y == 0) ? q : (blockIdx.y == 1) ? k : v;
    const int n = NBN * DD * SS;
    float m = 0.0f;
    for (int i = (blockIdx.x * 256 + threadIdx.x) * 4; i < n; i += gridDim.x * 256 * 4) {
        float4 x = *(const float4*)(src + i);
        m = fmaxf(m, fmaxf(fmaxf(fabsf(x.x), fabsf(x.y)), fmaxf(fabsf(x.z), fabsf(x.w))));
    }
    __shared__ float red[256];
    red[threadIdx.x] = m;
    __syncthreads();
    for (int off = 128; off > 0; off >>= 1) {
        if (threadIdx.x < off) red[threadIdx.x] = fmaxf(red[threadIdx.x], red[threadIdx.x + off]);
        __syncthreads();
    }
    if (threadIdx.x == 0) atomicMax(st + blockIdx.y, __float_as_uint(red[0]));
}

// Fused quantize kernel. grid (16, 64, 3), 256 threads.
// z<2: Q/K quantize + transpose-pack via LDS tile (float4 loads, coalesced int4 stores):
//      dst[bn][s][j] = pack_i8(iq[4j..4j+3][s]), j=0..15
// z=2: V quantize + pack into PV B-fragment order (unchanged layout).
__global__ void k_quant_qkv(const float* __restrict__ q, const float* __restrict__ k,
                            const float* __restrict__ v, const unsigned* __restrict__ st,
                            int* __restrict__ Qp, int* __restrict__ Kp, int* __restrict__ Vq) {
    __shared__ float TlA[64][69];                 // [d][s_loc], stride 69: 2-way max on r/w
    __shared__ __align__(16) int TlB[64][20];
    const int which = blockIdx.z;
    const int bn = blockIdx.y;
    const int tid = threadIdx.x;
    if (which < 2) {
        const float* tsrc = (which ? k : q) + (size_t)bn * DD * SS;
        int* dst = which ? Kp : Qp;
        const float sc = mkscale(st[which], 127.0f);
        const int s_base = blockIdx.x * 64;
        #pragma unroll
        for (int kk = 0; kk < 4; ++kk) {
            int idx = tid + kk * 256;             // 0..1023
            int d = idx >> 4, s4 = idx & 15;
            float4 x = *(const float4*)(tsrc + (size_t)d * SS + s_base + s4 * 4);
            TlA[d][s4*4+0] = x.x; TlA[d][s4*4+1] = x.y;
            TlA[d][s4*4+2] = x.z; TlA[d][s4*4+3] = x.w;
        }
        __syncthreads();
        const int u = tid & 3, s_loc = tid >> 2;
        int pw[4];
        #pragma unroll
        for (int jj = 0; jj < 4; ++jj) {
            int p = 0;
            #pragma unroll
            for (int r = 0; r < 4; ++r) {
                int iq = quant_sym(TlA[16*u + 4*jj + r][s_loc], sc);
                p |= (iq & 0xff) << (8 * r);
            }
            pw[jj] = p;
        }
        *(int4*)(dst + ((size_t)bn * SS + s_base + s_loc) * 16 + u * 4)
            = make_int4(pw[0], pw[1], pw[2], pw[3]);
    } else {
        const float sc = mkscale(st[2], 127.0f);
        const int tb = blockIdx.x;
        {
            const int d = tid >> 2, tqq = tid & 3;
            #pragma unroll
            for (int i = 0; i < 4; ++i) {
                const int tq = tqq * 4 + i;
                float4 x = *(const float4*)(v + (size_t)(bn * 64 + d) * SS + tb * 64 + tq * 4);
                TlB[d][tq] = (quant_sym(x.x, sc) & 0xff)
                          | ((quant_sym(x.y, sc) & 0xff) << 8)
                          | ((quant_sym(x.z, sc) & 0xff) << 16)
                          | ((quant_sym(x.w, sc) & 0xff) << 24);
            }
        }
        __syncthreads();
        {
            const int dt = tid >> 6, gg = (tid >> 4) & 3;
            const int d = dt * 16 + (tid & 15);
            int4 w = make_int4(TlB[d][gg*4+0], TlB[d][gg*4+1], TlB[d][gg*4+2], TlB[d][gg*4+3]);
            *(int4*)(Vq + (size_t)(bn * 16 + tb) * 1024 + tid * 4) = w;
        }
    }
}

// Phase A: 8 waves/block; wave = 32 s-rows (2 tiles) x 128 t's off the SAME 8 K-fragments.
// sched_barrier pins all 8 K loads in flight before any MFMA. Native v_exp_f32.
// XCD swizzle: bn = ((x&7)<<3)|((x>>3)&7).
__global__ __launch_bounds__(512) void k_phase_a(const int* __restrict__ Qp,
    const int* __restrict__ Kp, const unsigned* __restrict__ st,
    float* __restrict__ m2_arr, float* __restrict__ l_arr, unsigned* __restrict__ minl)
{
    __shared__ int   Mi[8][32];
    __shared__ float Lf[8][32];
    const int x = blockIdx.x;
    const int bn = ((x & 7) << 3) | ((x >> 3) & 7);
    const int s0 = blockIdx.y * 32;
    const int tid = threadIdx.x;
    const int wv = tid >> 6, lane = tid & 63;
    const int g = lane >> 4, c = lane & 15;
    const float sq = mkscale(st[0], 127.0f);
    const float sk = mkscale(st[1], 127.0f);
    const float cqk2 = (sq * sk * 0.125f) * 1.4426950408889634f;  // log2-domain
    const i32x4_ qf0 = *(const i32x4_*)(Qp + ((size_t)bn * SS + s0 + c) * 16 + g * 4);
    const i32x4_ qf1 = *(const i32x4_*)(Qp + ((size_t)bn * SS + s0 + 16 + c) * 16 + g * 4);
    const i32x4_ zero = {0, 0, 0, 0};
    const int* kb = Kp + ((size_t)bn * SS + wv * 128 + c) * 16 + g * 4;

    i32x4_ kfr[8];
    #pragma unroll
    for (int j = 0; j < 8; ++j) kfr[j] = *(const i32x4_*)(kb + j * 256);
    __builtin_amdgcn_sched_barrier(0);                     // all 8 loads issued before compute
    i32x4_ dq0[8], dq1[8];
    #pragma unroll
    for (int j = 0; j < 8; ++j) {
        dq0[j] = mfma_i8(kfr[j], qf0, zero);   // s = s0+c,    t = wv*128+16j+4g+r
        dq1[j] = mfma_i8(kfr[j], qf1, zero);   // s = s0+16+c, same t
    }

    int im0 = -2147483647, im1 = -2147483647;
    #pragma unroll
    for (int j = 0; j < 8; ++j) {
        im0 = max(im0, max(max(dq0[j][0], dq0[j][1]), max(dq0[j][2], dq0[j][3])));
        im1 = max(im1, max(max(dq1[j][0], dq1[j][1]), max(dq1[j][2], dq1[j][3])));
    }
    im0 = max(im0, __shfl_xor(im0, 16, 64));
    im0 = max(im0, __shfl_xor(im0, 32, 64));
    im1 = max(im1, __shfl_xor(im1, 16, 64));
    im1 = max(im1, __shfl_xor(im1, 32, 64));
    if (g == 0) { Mi[wv][c] = im0; Mi[wv][16 + c] = im1; }
    __syncthreads();
    {
        int a0 = Mi[0][c], a1 = Mi[0][16 + c];
        #pragma unroll
        for (int w = 1; w < 8; ++w) { a0 = max(a0, Mi[w][c]); a1 = max(a1, Mi[w][16 + c]); }
        im0 = a0; im1 = a1;
    }
    const float m20 = (float)im0 * cqk2;   // monotone => equals max of fl(dq*cqk2)
    const float m21 = (float)im1 * cqk2;
    float la0 = 0.0f, lb0 = 0.0f, lc0 = 0.0f, ld0 = 0.0f;
    float la1 = 0.0f, lb1 = 0.0f, lc1 = 0.0f, ld1 = 0.0f;
    #pragma unroll
    for (int j = 0; j < 8; ++j) {
        la0 += FEXP2(fmaf((float)dq0[j][0], cqk2, -m20));
        lb0 += FEXP2(fmaf((float)dq0[j][1], cqk2, -m20));
        lc0 += FEXP2(fmaf((float)dq0[j][2], cqk2, -m20));
        ld0 += FEXP2(fmaf((float)dq0[j][3], cqk2, -m20));
        la1 += FEXP2(fmaf((float)dq1[j][0], cqk2, -m21));
        lb1 += FEXP2(fmaf((float)dq1[j][1], cqk2, -m21));
        lc1 += FEXP2(fmaf((float)dq1[j][2], cqk2, -m21));
        ld1 += FEXP2(fmaf((float)dq1[j][3], cqk2, -m21));
    }
    float l0 = (la0 + lb0) + (lc0 + ld0);
    float l1 = (la1 + lb1) + (lc1 + ld1);
    l0 += __shfl_xor(l0, 16, 64);
    l0 += __shfl_xor(l0, 32, 64);
    l1 += __shfl_xor(l1, 16, 64);
    l1 += __shfl_xor(l1, 32, 64);
    if (g == 0) { Lf[wv][c] = l0; Lf[wv][16 + c] = l1; }
    __syncthreads();
    if (tid < 32) {
        const int cc = tid;
        float lr = ((Lf[0][cc] + Lf[1][cc]) + (Lf[2][cc] + Lf[3][cc]))
                 + ((Lf[4][cc] + Lf[5][cc]) + (Lf[6][cc] + Lf[7][cc]));
        int imr = Mi[0][cc];
        #pragma unroll
        for (int w = 1; w < 8; ++w) imr = max(imr, Mi[w][cc]);
        m2_arr[bn * SS + s0 + cc] = (float)imr * cqk2;
        l_arr[bn * SS + s0 + cc] = lr;
        float lm = lr;
        #pragma unroll
        for (int mk = 1; mk <= 16; mk <<= 1) lm = fminf(lm, __shfl_xor(lm, mk, 64));
        if (cc == 0) atomicMin(minl, __float_as_uint(lm));  // l > 0: uint order == float order
    }
}

// Phase B: 8 waves/block = 4 s-groups x 2 t-halves; prefetch pinned ahead of compute.
// Quant chain: k1 = rint(exp2(dq*cqk2+bexp)) (x<=255.0001, no clamp needed); pack k1 bytes;
// k2 word = (w>>1)&0x7f7f7f7f  [proof: rint(k1*127/255) == k1>>1 for all k1 in 0..255,
// and the ref's extra scale roundings perturb by ~2e-5 << 2e-3 boundary margin].
__global__ __launch_bounds__(512) void k_phase_b(const int* __restrict__ Qp,
    const int* __restrict__ Kp, const int* __restrict__ Vq,
    const unsigned* __restrict__ st, const float* __restrict__ m2_arr,
    const float* __restrict__ l_arr, const unsigned* __restrict__ minl,
    float* __restrict__ out)
{
    __shared__ __align__(16) int Pl[8 * 320];    // per-wave 16 x 20-word stride
    __shared__ __align__(16) int sbuf[64 * 67];  // [d][s_local] stride 67: max 2-way banks
    const int f = blockIdx.x + (blockIdx.y << 4);          // grid (16,64) flat
    const int bn = ((f & 7) << 3) | ((f >> 3) & 7);
    const int sblk = (f >> 6) * 64;
    const int tid = threadIdx.x;
    const int wv = tid >> 6, lane = tid & 63;
    const int g = lane >> 4, c = lane & 15;
    const int sgrp = wv & 3, th = wv >> 2;
    const int s0 = sblk + sgrp * 16;
    const float sq = mkscale(st[0], 127.0f);
    const float sk = mkscale(st[1], 127.0f);
    const float sv = mkscale(st[2], 127.0f);
    const float cqk2 = (sq * sk * 0.125f) * 1.4426950408889634f;
    const float maxP     = 1.0f / __uint_as_float(*minl);
    const float scale_p  = fmaxf(maxP / 255.0f, 1e-8f);
    const float scale_p2 = fmaxf((255.0f * scale_p) / 127.0f, 1e-8f);
    const float cpv = scale_p2 * sv;
    const float m2 = m2_arr[bn * SS + s0 + c];
    const float l  = l_arr [bn * SS + s0 + c];
    const float bexp = log2f((1.0f / scale_p) / l) - m2;   // x = exp2(dq*cqk2 + bexp)
    const i32x4_ qf = *(const i32x4_*)(Qp + ((size_t)bn * SS + s0 + c) * 16 + g * 4);
    const i32x4_ zero = {0, 0, 0, 0};
    const int* kbase = Kp + ((size_t)bn * SS + c) * 16 + g * 4;   // + t*16 words
    const int* vbase = Vq + (size_t)bn * 16384 + g * 64 + c * 4;  // + tb*1024 + dt*256
    int* myP = Pl + wv * 320;
    const int woff = c * 20 + g * 4;
    const int tb0 = th * 8;

    i32x4_ acc[4] = {zero, zero, zero, zero};
    i32x4_ kf[4], kn[4], vf[4], vn[4];
    #pragma unroll
    for (int j = 0; j < 4; ++j) kf[j] = *(const i32x4_*)(kbase + (tb0 * 64 + j * 16) * 16);
    #pragma unroll
    for (int dt = 0; dt < 4; ++dt) vf[dt] = *(const i32x4_*)(vbase + tb0 * 1024 + dt * 256);

    #pragma unroll
    for (int i = 0; i < 8; ++i) {
        const int tb = tb0 + i;
        if (i < 7) {                                     // issue next-iter loads (8 in flight)
            #pragma unroll
            for (int j = 0; j < 4; ++j) kn[j] = *(const i32x4_*)(kbase + ((tb + 1) * 64 + j * 16) * 16);
            #pragma unroll
            for (int dt = 0; dt < 4; ++dt) vn[dt] = *(const i32x4_*)(vbase + (tb + 1) * 1024 + dt * 256);
        }
        __builtin_amdgcn_sched_barrier(0);               // loads stay above the compute
        int W[4];
        #pragma unroll
        for (int j = 0; j < 4; ++j) {                    // QK + quantize P (hides the loads)
            i32x4_ dq = mfma_i8(kf[j], qf, zero);
            int w = 0;
            #pragma unroll
            for (int r = 0; r < 4; ++r) {
                float xx = FEXP2(fmaf((float)dq[r], cqk2, bexp));
                int k1 = (int)rintf(xx);                 // 0..255 exact
                w |= k1 << (8 * r);
            }
            W[j] = (w >> 1) & 0x7f7f7f7f;                // per-byte k2 = k1>>1
        }
        i32x4_ wv4 = {W[0], W[1], W[2], W[3]};
        *(i32x4_*)(myP + woff) = wv4;                    // publish W(tb)
        i32x4_ pa;                                       // word-transpose read
        pa[0] = myP[c * 20 + 0 + g];
        pa[1] = myP[c * 20 + 4 + g];
        pa[2] = myP[c * 20 + 8 + g];
        pa[3] = myP[c * 20 + 12 + g];
        #pragma unroll
        for (int dt = 0; dt < 4; ++dt) acc[dt] = mfma_i8(pa, vf[dt], acc[dt]);
        #pragma unroll
        for (int j = 0; j < 4; ++j) kf[j] = kn[j];
        #pragma unroll
        for (int dt = 0; dt < 4; ++dt) vf[dt] = vn[dt];
    }

    // acc lane (c,g) reg (dt,r): d = dt*16 + c, s_local = sgrp*16 + 4g + r
    if (th == 0) {
        #pragma unroll
        for (int dt = 0; dt < 4; ++dt)
            #pragma unroll
            for (int r = 0; r < 4; ++r)
                sbuf[(dt * 16 + c) * 67 + sgrp * 16 + 4 * g + r] = acc[dt][r];
    }
    __syncthreads();
    if (th == 1) {
        #pragma unroll
        for (int dt = 0; dt < 4; ++dt)
            #pragma unroll
            for (int r = 0; r < 4; ++r) {
                const int slot = (dt * 16 + c) * 67 + sgrp * 16 + 4 * g + r;
                ((float*)sbuf)[slot] = (float)(sbuf[slot] + acc[dt][r]) * cpv;
            }
    }
    __syncthreads();
    #pragma unroll
    for (int u = 0; u < 2; ++u) {
        const int chunk = tid + u * 512;         // 0..1023
        const int d = chunk >> 4, sq4 = chunk & 15;
        const float* fb = (const float*)sbuf + d * 67 + sq4 * 4;
        float4 val = make_float4(fb[0], fb[1], fb[2], fb[3]);
        *(float4*)(out + (size_t)bn * 65536 + (size_t)d * 1024 + sblk + sq4 * 4) = val;
    }
}

extern "C" void kernel_launch(void* const* d_in, const int* in_sizes, int n_in,
                              void* d_out, int out_size, void* d_ws, size_t ws_size,
                              hipStream_t stream) {
    const float* q = (const float*)d_in[0];
    const float* k = (const float*)d_in[1];
    const float* v = (const float*)d_in[2];
    float* out = (float*)d_out;
    char* ws = (char*)d_ws;

    unsigned* st = (unsigned*)ws;                                 // [0..2]=amax q,k,v  [3]=min_l
    int* Qp      = (int*)(ws + 1024);                             // 4 MB
    int* Kp      = (int*)(ws + 1024 + (size_t)(1 << 22));         // 4 MB
    int* Vq      = (int*)(ws + 1024 + (size_t)(2 << 22));         // 4 MB (B-fragment order)
    float* m2    = (float*)(ws + 1024 + (size_t)(3 << 22));       // 256 KB
    float* l_a   = (float*)(ws + 1024 + (size_t)(3 << 22) + (1 << 18)); // 256 KB

    k_init<<<1, 64, 0, stream>>>(st);
    k_absmax<<<dim3(256, 3), 256, 0, stream>>>(q, k, v, st);
    k_quant_qkv<<<dim3(16, NBN, 3), 256, 0, stream>>>(q, k, v, st, Qp, Kp, Vq);
    k_phase_a<<<dim3(64, 32), 512, 0, stream>>>(Qp, Kp, st, m2, l_a, st + 3);
    k_phase_b<<<dim3(16, NBN), 512, 0, stream>>>(Qp, Kp, Vq, st, m2, l_a, st + 3, out);
}

// Round 8
// 87.653 us; speedup vs baseline: 6.3500x; 1.0568x over previous
//
#include <hip/hip_runtime.h>
#include <math.h>

#define NBN 64      // B*N_HEADS
#define DD  64      // head dim
#define SS  1024    // sequence length (H*W)

typedef int i32x4_ __attribute__((ext_vector_type(4)));

// raw v_exp_f32 (no OCML denormal wrapper). Args here are always well in range.
#if defined(__has_builtin)
#  if __has_builtin(__builtin_amdgcn_exp2f)
#    define FEXP2(x) __builtin_amdgcn_exp2f(x)
#  endif
#endif
#ifndef FEXP2
#  define FEXP2(x) exp2f(x)
#endif

// single-instruction byte insert: D = (u8(S0) << 8*r) | (old & ~mask). Input is
// pre-rounded via rintf so any cvt rounding mode gives the identical result.
#if defined(__has_builtin)
#  if __has_builtin(__builtin_amdgcn_cvt_pk_u8_f32)
#    define PK_U8(f, r, old) __builtin_amdgcn_cvt_pk_u8_f32((f), (r), (old))
#  endif
#endif
#ifndef PK_U8
#  define PK_U8(f, r, old) (((old) & ~(0xff << (8*(r)))) | (((int)(f) & 0xff) << (8*(r))))
#endif

__device__ __forceinline__ i32x4_ mfma_i8(i32x4_ a, i32x4_ b, i32x4_ c) {
    // D[m][n] += sum_k A[m][k]*B[n][k]; A/B lane: m/n = lane&15, k = (lane>>4)*16 + reg*4 + byte
    // C/D: col(n) = lane&15, row(m) = (lane>>4)*4 + reg
    return __builtin_amdgcn_mfma_i32_16x16x64_i8(a, b, c, 0, 0, 0);
}

__device__ __forceinline__ float mkscale(unsigned bits, float qmax) {
    return fmaxf(__uint_as_float(bits) / qmax, 1e-8f);   // jnp.maximum(absmax/qmax, 1e-8)
}

__device__ __forceinline__ int quant_sym(float x, float sc) {
    float r = fminf(fmaxf(rintf(x / sc), -127.0f), 127.0f);  // round-half-even == jnp.round
    return (int)r;
}

__global__ void k_absmax(const float* __restrict__ q, const float* __restrict__ k,
                         const float* __restrict__ v, unsigned* __restrict__ st) {
    const float* src = (blockIdx.y == 0) ? q : (blockIdx.y == 1) ? k : v;
    const int n = NBN * DD * SS;
    float m = 0.0f;
    for (int i = (blockIdx.x * 256 + threadIdx.x) * 4; i < n; i += gridDim.x * 256 * 4) {
        float4 x = *(const float4*)(src + i);
        m = fmaxf(m, fmaxf(fmaxf(fabsf(x.x), fabsf(x.y)), fmaxf(fabsf(x.z), fabsf(x.w))));
    }
    __shared__ float red[256];
    red[threadIdx.x] = m;
    __syncthreads();
    for (int off = 128; off > 0; off >>= 1) {
        if (threadIdx.x < off) red[threadIdx.x] = fmaxf(red[threadIdx.x], red[threadIdx.x + off]);
        __syncthreads();
    }
    if (threadIdx.x == 0) atomicMax(st + blockIdx.y, __float_as_uint(red[0]));
}

// Fused quantize kernel. grid (16, 64, 3), 256 threads.
// z<2: Q/K quantize + transpose-pack via LDS tile; z=2: V pack into PV B-fragment order.
__global__ void k_quant_qkv(const float* __restrict__ q, const float* __restrict__ k,
                            const float* __restrict__ v, const unsigned* __restrict__ st,
                            int* __restrict__ Qp, int* __restrict__ Kp, int* __restrict__ Vq) {
    __shared__ float TlA[64][69];
    __shared__ __align__(16) int TlB[64][20];
    const int which = blockIdx.z;
    const int bn = blockIdx.y;
    const int tid = threadIdx.x;
    if (which < 2) {
        const float* tsrc = (which ? k : q) + (size_t)bn * DD * SS;
        int* dst = which ? Kp : Qp;
        const float sc = mkscale(st[which], 127.0f);
        const int s_base = blockIdx.x * 64;
        #pragma unroll
        for (int kk = 0; kk < 4; ++kk) {
            int idx = tid + kk * 256;
            int d = idx >> 4, s4 = idx & 15;
            float4 x = *(const float4*)(tsrc + (size_t)d * SS + s_base + s4 * 4);
            TlA[d][s4*4+0] = x.x; TlA[d][s4*4+1] = x.y;
            TlA[d][s4*4+2] = x.z; TlA[d][s4*4+3] = x.w;
        }
        __syncthreads();
        const int u = tid & 3, s_loc = tid >> 2;
        int pw[4];
        #pragma unroll
        for (int jj = 0; jj < 4; ++jj) {
            int p = 0;
            #pragma unroll
            for (int r = 0; r < 4; ++r) {
                int iq = quant_sym(TlA[16*u + 4*jj + r][s_loc], sc);
                p |= (iq & 0xff) << (8 * r);
            }
            pw[jj] = p;
        }
        *(int4*)(dst + ((size_t)bn * SS + s_base + s_loc) * 16 + u * 4)
            = make_int4(pw[0], pw[1], pw[2], pw[3]);
    } else {
        const float sc = mkscale(st[2], 127.0f);
        const int tb = blockIdx.x;
        {
            const int d = tid >> 2, tqq = tid & 3;
            #pragma unroll
            for (int i = 0; i < 4; ++i) {
                const int tq = tqq * 4 + i;
                float4 x = *(const float4*)(v + (size_t)(bn * 64 + d) * SS + tb * 64 + tq * 4);
                TlB[d][tq] = (quant_sym(x.x, sc) & 0xff)
                          | ((quant_sym(x.y, sc) & 0xff) << 8)
                          | ((quant_sym(x.z, sc) & 0xff) << 16)
                          | ((quant_sym(x.w, sc) & 0xff) << 24);
            }
        }
        __syncthreads();
        {
            const int dt = tid >> 6, gg = (tid >> 4) & 3;
            const int d = dt * 16 + (tid & 15);
            int4 w = make_int4(TlB[d][gg*4+0], TlB[d][gg*4+1], TlB[d][gg*4+2], TlB[d][gg*4+3]);
            *(int4*)(Vq + (size_t)(bn * 16 + tb) * 1024 + tid * 4) = w;
        }
    }
}

// Phase A: 8 waves/block; wave = 32 s-rows x 128 t's off the SAME 8 K-fragments.
// minl stored as COMPLEMENTED bits: atomicMax(~bits) == min over positive floats (init 0).
__global__ __launch_bounds__(512) void k_phase_a(const int* __restrict__ Qp,
    const int* __restrict__ Kp, const unsigned* __restrict__ st,
    float* __restrict__ m2_arr, float* __restrict__ l_arr, unsigned* __restrict__ minl)
{
    __shared__ int   Mi[8][32];
    __shared__ float Lf[8][32];
    const int x = blockIdx.x;
    const int bn = ((x & 7) << 3) | ((x >> 3) & 7);
    const int s0 = blockIdx.y * 32;
    const int tid = threadIdx.x;
    const int wv = tid >> 6, lane = tid & 63;
    const int g = lane >> 4, c = lane & 15;
    const float sq = mkscale(st[0], 127.0f);
    const float sk = mkscale(st[1], 127.0f);
    const float cqk2 = (sq * sk * 0.125f) * 1.4426950408889634f;  // log2-domain
    const i32x4_ qf0 = *(const i32x4_*)(Qp + ((size_t)bn * SS + s0 + c) * 16 + g * 4);
    const i32x4_ qf1 = *(const i32x4_*)(Qp + ((size_t)bn * SS + s0 + 16 + c) * 16 + g * 4);
    const i32x4_ zero = {0, 0, 0, 0};
    const int* kb = Kp + ((size_t)bn * SS + wv * 128 + c) * 16 + g * 4;

    i32x4_ kfr[8];
    #pragma unroll
    for (int j = 0; j < 8; ++j) kfr[j] = *(const i32x4_*)(kb + j * 256);
    __builtin_amdgcn_sched_barrier(0);
    i32x4_ dq0[8], dq1[8];
    #pragma unroll
    for (int j = 0; j < 8; ++j) {
        dq0[j] = mfma_i8(kfr[j], qf0, zero);
        dq1[j] = mfma_i8(kfr[j], qf1, zero);
    }

    int im0 = -2147483647, im1 = -2147483647;
    #pragma unroll
    for (int j = 0; j < 8; ++j) {
        im0 = max(im0, max(max(dq0[j][0], dq0[j][1]), max(dq0[j][2], dq0[j][3])));
        im1 = max(im1, max(max(dq1[j][0], dq1[j][1]), max(dq1[j][2], dq1[j][3])));
    }
    im0 = max(im0, __shfl_xor(im0, 16, 64));
    im0 = max(im0, __shfl_xor(im0, 32, 64));
    im1 = max(im1, __shfl_xor(im1, 16, 64));
    im1 = max(im1, __shfl_xor(im1, 32, 64));
    if (g == 0) { Mi[wv][c] = im0; Mi[wv][16 + c] = im1; }
    __syncthreads();
    {
        int a0 = Mi[0][c], a1 = Mi[0][16 + c];
        #pragma unroll
        for (int w = 1; w < 8; ++w) { a0 = max(a0, Mi[w][c]); a1 = max(a1, Mi[w][16 + c]); }
        im0 = a0; im1 = a1;
    }
    const float m20 = (float)im0 * cqk2;
    const float m21 = (float)im1 * cqk2;
    float la0 = 0.0f, lb0 = 0.0f, lc0 = 0.0f, ld0 = 0.0f;
    float la1 = 0.0f, lb1 = 0.0f, lc1 = 0.0f, ld1 = 0.0f;
    #pragma unroll
    for (int j = 0; j < 8; ++j) {
        la0 += FEXP2(fmaf((float)dq0[j][0], cqk2, -m20));
        lb0 += FEXP2(fmaf((float)dq0[j][1], cqk2, -m20));
        lc0 += FEXP2(fmaf((float)dq0[j][2], cqk2, -m20));
        ld0 += FEXP2(fmaf((float)dq0[j][3], cqk2, -m20));
        la1 += FEXP2(fmaf((float)dq1[j][0], cqk2, -m21));
        lb1 += FEXP2(fmaf((float)dq1[j][1], cqk2, -m21));
        lc1 += FEXP2(fmaf((float)dq1[j][2], cqk2, -m21));
        ld1 += FEXP2(fmaf((float)dq1[j][3], cqk2, -m21));
    }
    float l0 = (la0 + lb0) + (lc0 + ld0);
    float l1 = (la1 + lb1) + (lc1 + ld1);
    l0 += __shfl_xor(l0, 16, 64);
    l0 += __shfl_xor(l0, 32, 64);
    l1 += __shfl_xor(l1, 16, 64);
    l1 += __shfl_xor(l1, 32, 64);
    if (g == 0) { Lf[wv][c] = l0; Lf[wv][16 + c] = l1; }
    __syncthreads();
    if (tid < 32) {
        const int cc = tid;
        float lr = ((Lf[0][cc] + Lf[1][cc]) + (Lf[2][cc] + Lf[3][cc]))
                 + ((Lf[4][cc] + Lf[5][cc]) + (Lf[6][cc] + Lf[7][cc]));
        int imr = Mi[0][cc];
        #pragma unroll
        for (int w = 1; w < 8; ++w) imr = max(imr, Mi[w][cc]);
        m2_arr[bn * SS + s0 + cc] = (float)imr * cqk2;
        l_arr[bn * SS + s0 + cc] = lr;
        float lm = lr;
        #pragma unroll
        for (int mk = 1; mk <= 16; mk <<= 1) lm = fminf(lm, __shfl_xor(lm, mk, 64));
        if (cc == 0) atomicMax(minl, ~__float_as_uint(lm));   // complement: max(~b) == min l
    }
}

// Phase B: 8 waves = 4 s-groups x 2 t-halves. K/V tiles double-buffered in LDS
// (T14 reg-staged split: issue loads -> compute -> ds_write -> barrier), killing the
// 4x L2 redundancy across sgrp waves. Quant: exp2 -> rintf -> v_cvt_pk_u8_f32, then
// per-word k2 = (w>>1)&0x7f7f7f7f. Epilogue combine reuses the Pl LDS region.
__global__ __launch_bounds__(512) void k_phase_b(const int* __restrict__ Qp,
    const int* __restrict__ Kp, const int* __restrict__ Vq,
    const unsigned* __restrict__ st, const float* __restrict__ m2_arr,
    const float* __restrict__ l_arr, const unsigned* __restrict__ minl,
    float* __restrict__ out)
{
    __shared__ __align__(16) int Kst[2][2][1024];   // [buf][th][tile] 16 KB
    __shared__ __align__(16) int Vst[2][2][1024];   // 16 KB
    __shared__ __align__(16) int PlS[2816];         // Pl (8x320=2560) / epilogue sbuf (32x67=2144)
    const int f = blockIdx.x + (blockIdx.y << 4);
    const int bn = ((f & 7) << 3) | ((f >> 3) & 7);
    const int sblk = (f >> 6) * 64;
    const int tid = threadIdx.x;
    const int wv = tid >> 6, lane = tid & 63;
    const int g = lane >> 4, c = lane & 15;
    const int sgrp = wv & 3, th = wv >> 2;
    const int s0 = sblk + sgrp * 16;
    const float sq = mkscale(st[0], 127.0f);
    const float sk = mkscale(st[1], 127.0f);
    const float sv = mkscale(st[2], 127.0f);
    const float cqk2 = (sq * sk * 0.125f) * 1.4426950408889634f;
    const float maxP     = 1.0f / __uint_as_float(~(*minl));
    const float scale_p  = fmaxf(maxP / 255.0f, 1e-8f);
    const float scale_p2 = fmaxf((255.0f * scale_p) / 127.0f, 1e-8f);
    const float cpv = scale_p2 * sv;
    const float m2 = m2_arr[bn * SS + s0 + c];
    const float l  = l_arr [bn * SS + s0 + c];
    const float bexp = log2f((1.0f / scale_p) / l) - m2;   // x = exp2(dq*cqk2 + bexp)
    const i32x4_ qf = *(const i32x4_*)(Qp + ((size_t)bn * SS + s0 + c) * 16 + g * 4);
    const i32x4_ zero = {0, 0, 0, 0};
    int* myP = PlS + wv * 320;
    const int woff = c * 20 + g * 4;
    const int tb0 = th * 8;
    // staging addresses: wave (sgrp,th) stages quarter sgrp of its th tile; lane covers 4 words
    const int soff = sgrp * 256 + lane * 4;
    const int* kg = Kp + (size_t)bn * SS * 16 + soff;   // + tb*1024
    const int* vg = Vq + (size_t)bn * 16384 + soff;     // + tb*1024

    i32x4_ acc[4] = {zero, zero, zero, zero};

    {   // prologue: stage tb0 into buf 0
        i32x4_ gk = *(const i32x4_*)(kg + tb0 * 1024);
        i32x4_ gv = *(const i32x4_*)(vg + tb0 * 1024);
        *(i32x4_*)&Kst[0][th][soff] = gk;
        *(i32x4_*)&Vst[0][th][soff] = gv;
    }
    __syncthreads();

    #pragma unroll
    for (int i = 0; i < 8; ++i) {
        const int b = i & 1;
        i32x4_ gk, gv;
        if (i < 7) {                                   // issue next tile's loads early
            gk = *(const i32x4_*)(kg + (tb0 + i + 1) * 1024);
            gv = *(const i32x4_*)(vg + (tb0 + i + 1) * 1024);
        }
        __builtin_amdgcn_sched_barrier(0);
        int W[4];
        #pragma unroll
        for (int j = 0; j < 4; ++j) {                  // QK + quantize P
            i32x4_ kf = *(const i32x4_*)&Kst[b][th][j * 256 + c * 16 + g * 4];
            i32x4_ dq = mfma_i8(kf, qf, zero);
            int w = 0;
            #pragma unroll
            for (int r = 0; r < 4; ++r) {
                float xx = FEXP2(fmaf((float)dq[r], cqk2, bexp));
                w = PK_U8(rintf(xx), r, w);            // k1 byte insert (exact: pre-rounded)
            }
            W[j] = (w >> 1) & 0x7f7f7f7f;              // per-byte k2 = k1>>1
        }
        i32x4_ wv4 = {W[0], W[1], W[2], W[3]};
        *(i32x4_*)(myP + woff) = wv4;                  // publish W(tb)
        i32x4_ pa;                                     // word-transpose read
        pa[0] = myP[c * 20 + 0 + g];
        pa[1] = myP[c * 20 + 4 + g];
        pa[2] = myP[c * 20 + 8 + g];
        pa[3] = myP[c * 20 + 12 + g];
        #pragma unroll
        for (int dt = 0; dt < 4; ++dt) {
            i32x4_ vf = *(const i32x4_*)&Vst[b][th][dt * 256 + g * 64 + c * 4];
            acc[dt] = mfma_i8(pa, vf, acc[dt]);
        }
        if (i < 7) {                                   // land next tile (hides load latency)
            *(i32x4_*)&Kst[b ^ 1][th][soff] = gk;
            *(i32x4_*)&Vst[b ^ 1][th][soff] = gv;
        }
        __syncthreads();
    }

    // epilogue: combine t-halves (exact int add) + scale + coalesced store, 2 d-chunks,
    // reusing PlS as sbuf[32][67].
    int* sbuf = PlS;
    #pragma unroll
    for (int ch = 0; ch < 2; ++ch) {
        if (th == 0) {
            #pragma unroll
            for (int dt = 0; dt < 2; ++dt)
                #pragma unroll
                for (int r = 0; r < 4; ++r)
                    sbuf[(dt * 16 + c) * 67 + sgrp * 16 + 4 * g + r] = acc[ch * 2 + dt][r];
        }
        __syncthreads();
        if (th == 1) {
            #pragma unroll
            for (int dt = 0; dt < 2; ++dt)
                #pragma unroll
                for (int r = 0; r < 4; ++r) {
                    const int slot = (dt * 16 + c) * 67 + sgrp * 16 + 4 * g + r;
                    ((float*)sbuf)[slot] = (float)(sbuf[slot] + acc[ch * 2 + dt][r]) * cpv;
                }
        }
        __syncthreads();
        if (tid < 512) {
            const int d = tid >> 4, sq4 = tid & 15;
            const float* fb = (const float*)sbuf + d * 67 + sq4 * 4;
            float4 val = make_float4(fb[0], fb[1], fb[2], fb[3]);
            *(float4*)(out + (size_t)bn * 65536 + (size_t)(ch * 32 + d) * 1024 + sblk + sq4 * 4) = val;
        }
        __syncthreads();
    }
}

extern "C" void kernel_launch(void* const* d_in, const int* in_sizes, int n_in,
                              void* d_out, int out_size, void* d_ws, size_t ws_size,
                              hipStream_t stream) {
    const float* q = (const float*)d_in[0];
    const float* k = (const float*)d_in[1];
    const float* v = (const float*)d_in[2];
    float* out = (float*)d_out;
    char* ws = (char*)d_ws;

    unsigned* st = (unsigned*)ws;                                 // [0..2]=amax q,k,v  [3]=~min_l bits
    int* Qp      = (int*)(ws + 1024);                             // 4 MB
    int* Kp      = (int*)(ws + 1024 + (size_t)(1 << 22));         // 4 MB
    int* Vq      = (int*)(ws + 1024 + (size_t)(2 << 22));         // 4 MB (B-fragment order)
    float* m2    = (float*)(ws + 1024 + (size_t)(3 << 22));       // 256 KB
    float* l_a   = (float*)(ws + 1024 + (size_t)(3 << 22) + (1 << 18)); // 256 KB

    hipMemsetAsync(st, 0, 16, stream);                            // amax=0, ~minl=0 (== minl=+inf)
    k_absmax<<<dim3(256, 3), 256, 0, stream>>>(q, k, v, st);
    k_quant_qkv<<<dim3(16, NBN, 3), 256, 0, stream>>>(q, k, v, st, Qp, Kp, Vq);
    k_phase_a<<<dim3(64, 32), 512, 0, stream>>>(Qp, Kp, st, m2, l_a, st + 3);
    k_phase_b<<<dim3(16, NBN), 512, 0, stream>>>(Qp, Kp, Vq, st, m2, l_a, st + 3, out);
}

// Round 9
// 66.145 us; speedup vs baseline: 8.4148x; 1.3252x over previous
//
#include <hip/hip_runtime.h>
#include <math.h>

#define NBN 64      // B*N_HEADS
#define DD  64      // head dim
#define SS  1024    // sequence length (H*W)

typedef int i32x4_ __attribute__((ext_vector_type(4)));

// raw v_exp_f32 (no OCML denormal wrapper). Args here are always well in range.
#if defined(__has_builtin)
#  if __has_builtin(__builtin_amdgcn_exp2f)
#    define FEXP2(x) __builtin_amdgcn_exp2f(x)
#  endif
#endif
#ifndef FEXP2
#  define FEXP2(x) exp2f(x)
#endif

// single-instruction byte insert: D = (u8(S0) << 8*r) | (old & ~mask). Input pre-rounded.
#if defined(__has_builtin)
#  if __has_builtin(__builtin_amdgcn_cvt_pk_u8_f32)
#    define PK_U8(f, r, old) __builtin_amdgcn_cvt_pk_u8_f32((f), (r), (old))
#  endif
#endif
#ifndef PK_U8
#  define PK_U8(f, r, old) (((old) & ~(0xff << (8*(r)))) | (((int)(f) & 0xff) << (8*(r))))
#endif

__device__ __forceinline__ i32x4_ mfma_i8(i32x4_ a, i32x4_ b, i32x4_ c) {
    // D[m][n] += sum_k A[m][k]*B[n][k]; A/B lane: m/n = lane&15, k = (lane>>4)*16 + reg*4 + byte
    // C/D: col(n) = lane&15, row(m) = (lane>>4)*4 + reg
    return __builtin_amdgcn_mfma_i32_16x16x64_i8(a, b, c, 0, 0, 0);
}

__device__ __forceinline__ int quant_sym(float x, float sc) {
    float r = fminf(fmaxf(rintf(x / sc), -127.0f), 127.0f);  // round-half-even == jnp.round
    return (int)r;
}

// wave-parallel max over 256 partials (float4/lane + 6 shuffles); max is order-independent.
__device__ __forceinline__ float wave_max256(const float* part, int lane) {
    float4 t = ((const float4*)part)[lane];
    float m = fmaxf(fmaxf(t.x, t.y), fmaxf(t.z, t.w));
    #pragma unroll
    for (int mk = 1; mk <= 32; mk <<= 1) m = fmaxf(m, __shfl_xor(m, mk, 64));
    return m;
}

// wave-parallel min over 2048 partials.
__device__ __forceinline__ float wave_min2048(const float* part, int lane) {
    float4 t = ((const float4*)part)[lane];
    float m = fminf(fminf(t.x, t.y), fminf(t.z, t.w));
    #pragma unroll
    for (int i = 1; i < 8; ++i) {
        float4 u = ((const float4*)part)[lane + i * 64];
        m = fminf(m, fminf(fminf(u.x, u.y), fminf(u.z, u.w)));
    }
    #pragma unroll
    for (int mk = 1; mk <= 32; mk <<= 1) m = fminf(m, __shfl_xor(m, mk, 64));
    return m;
}

// absmax partials: no atomics, no init needed (every slot written every run).
__global__ void k_absmax(const float* __restrict__ q, const float* __restrict__ k,
                         const float* __restrict__ v, float* __restrict__ amax_part) {
    const float* src = (blockIdx.y == 0) ? q : (blockIdx.y == 1) ? k : v;
    const int n = NBN * DD * SS;
    float m = 0.0f;
    for (int i = (blockIdx.x * 256 + threadIdx.x) * 4; i < n; i += gridDim.x * 256 * 4) {
        float4 x = *(const float4*)(src + i);
        m = fmaxf(m, fmaxf(fmaxf(fabsf(x.x), fabsf(x.y)), fmaxf(fabsf(x.z), fabsf(x.w))));
    }
    __shared__ float red[256];
    red[threadIdx.x] = m;
    __syncthreads();
    for (int off = 128; off > 0; off >>= 1) {
        if (threadIdx.x < off) red[threadIdx.x] = fmaxf(red[threadIdx.x], red[threadIdx.x + off]);
        __syncthreads();
    }
    if (threadIdx.x == 0) amax_part[blockIdx.y * 256 + blockIdx.x] = red[0];
}

// Fused quantize kernel. grid (16, 64, 3), 256 threads.
// z<2: Q/K quantize + transpose-pack via LDS tile; z=2: V pack into PV B-fragment order.
__global__ void k_quant_qkv(const float* __restrict__ q, const float* __restrict__ k,
                            const float* __restrict__ v, const float* __restrict__ amax_part,
                            int* __restrict__ Qp, int* __restrict__ Kp, int* __restrict__ Vq) {
    __shared__ float TlA[64][69];
    __shared__ __align__(16) int TlB[64][20];
    const int which = blockIdx.z;
    const int bn = blockIdx.y;
    const int tid = threadIdx.x;
    const float sc = fmaxf(wave_max256(amax_part + which * 256, tid & 63) / 127.0f, 1e-8f);
    if (which < 2) {
        const float* tsrc = (which ? k : q) + (size_t)bn * DD * SS;
        int* dst = which ? Kp : Qp;
        const int s_base = blockIdx.x * 64;
        #pragma unroll
        for (int kk = 0; kk < 4; ++kk) {
            int idx = tid + kk * 256;
            int d = idx >> 4, s4 = idx & 15;
            float4 x = *(const float4*)(tsrc + (size_t)d * SS + s_base + s4 * 4);
            TlA[d][s4*4+0] = x.x; TlA[d][s4*4+1] = x.y;
            TlA[d][s4*4+2] = x.z; TlA[d][s4*4+3] = x.w;
        }
        __syncthreads();
        const int u = tid & 3, s_loc = tid >> 2;
        int pw[4];
        #pragma unroll
        for (int jj = 0; jj < 4; ++jj) {
            int p = 0;
            #pragma unroll
            for (int r = 0; r < 4; ++r) {
                int iq = quant_sym(TlA[16*u + 4*jj + r][s_loc], sc);
                p |= (iq & 0xff) << (8 * r);
            }
            pw[jj] = p;
        }
        *(int4*)(dst + ((size_t)bn * SS + s_base + s_loc) * 16 + u * 4)
            = make_int4(pw[0], pw[1], pw[2], pw[3]);
    } else {
        const int tb = blockIdx.x;
        {
            const int d = tid >> 2, tqq = tid & 3;
            #pragma unroll
            for (int i = 0; i < 4; ++i) {
                const int tq = tqq * 4 + i;
                float4 x = *(const float4*)(v + (size_t)(bn * 64 + d) * SS + tb * 64 + tq * 4);
                TlB[d][tq] = (quant_sym(x.x, sc) & 0xff)
                          | ((quant_sym(x.y, sc) & 0xff) << 8)
                          | ((quant_sym(x.z, sc) & 0xff) << 16)
                          | ((quant_sym(x.w, sc) & 0xff) << 24);
            }
        }
        __syncthreads();
        {
            const int dt = tid >> 6, gg = (tid >> 4) & 3;
            const int d = dt * 16 + (tid & 15);
            int4 w = make_int4(TlB[d][gg*4+0], TlB[d][gg*4+1], TlB[d][gg*4+2], TlB[d][gg*4+3]);
            *(int4*)(Vq + (size_t)(bn * 16 + tb) * 1024 + tid * 4) = w;
        }
    }
}

// Phase A: 8 waves/block; wave = 32 s-rows x 128 t's off the SAME 8 K-fragments.
// ONE barrier: wave-local max -> exp2 immediately; epilogue combines via
// l = sum_w l_w * exp2(m_w - m) (m bit-identical: fl monotone). minl as plain
// per-block partial store (no atomics).
__global__ __launch_bounds__(512) void k_phase_a(const int* __restrict__ Qp,
    const int* __restrict__ Kp, const float* __restrict__ amax_part,
    float* __restrict__ m2_arr, float* __restrict__ l_arr, float* __restrict__ minl_part)
{
    __shared__ float Mf[8][32];
    __shared__ float Lf[8][32];
    const int x = blockIdx.x;
    const int bn = ((x & 7) << 3) | ((x >> 3) & 7);   // XCD swizzle
    const int s0 = blockIdx.y * 32;
    const int tid = threadIdx.x;
    const int wv = tid >> 6, lane = tid & 63;
    const int g = lane >> 4, c = lane & 15;
    const float aq = wave_max256(amax_part, lane);
    const float ak = wave_max256(amax_part + 256, lane);
    const float sq = fmaxf(aq / 127.0f, 1e-8f);
    const float sk = fmaxf(ak / 127.0f, 1e-8f);
    const float cqk2 = (sq * sk * 0.125f) * 1.4426950408889634f;  // log2-domain
    const i32x4_ qf0 = *(const i32x4_*)(Qp + ((size_t)bn * SS + s0 + c) * 16 + g * 4);
    const i32x4_ qf1 = *(const i32x4_*)(Qp + ((size_t)bn * SS + s0 + 16 + c) * 16 + g * 4);
    const i32x4_ zero = {0, 0, 0, 0};
    const int* kb = Kp + ((size_t)bn * SS + wv * 128 + c) * 16 + g * 4;

    i32x4_ kfr[8];
    #pragma unroll
    for (int j = 0; j < 8; ++j) kfr[j] = *(const i32x4_*)(kb + j * 256);
    __builtin_amdgcn_sched_barrier(0);                 // all 8 loads in flight before compute
    i32x4_ dq0[8], dq1[8];
    #pragma unroll
    for (int j = 0; j < 8; ++j) {
        dq0[j] = mfma_i8(kfr[j], qf0, zero);           // s = s0+c,    t = wv*128+16j+4g+r
        dq1[j] = mfma_i8(kfr[j], qf1, zero);           // s = s0+16+c
    }

    // wave-local row max (integer, monotone), then exp2 sums IMMEDIATELY (no barrier wait)
    int im0 = -2147483647, im1 = -2147483647;
    #pragma unroll
    for (int j = 0; j < 8; ++j) {
        im0 = max(im0, max(max(dq0[j][0], dq0[j][1]), max(dq0[j][2], dq0[j][3])));
        im1 = max(im1, max(max(dq1[j][0], dq1[j][1]), max(dq1[j][2], dq1[j][3])));
    }
    im0 = max(im0, __shfl_xor(im0, 16, 64));
    im0 = max(im0, __shfl_xor(im0, 32, 64));
    im1 = max(im1, __shfl_xor(im1, 16, 64));
    im1 = max(im1, __shfl_xor(im1, 32, 64));
    const float m0 = (float)im0 * cqk2;                // wave-local max (float)
    const float m1 = (float)im1 * cqk2;
    float la0 = 0.0f, lb0 = 0.0f, lc0 = 0.0f, ld0 = 0.0f;
    float la1 = 0.0f, lb1 = 0.0f, lc1 = 0.0f, ld1 = 0.0f;
    #pragma unroll
    for (int j = 0; j < 8; ++j) {
        la0 += FEXP2(fmaf((float)dq0[j][0], cqk2, -m0));
        lb0 += FEXP2(fmaf((float)dq0[j][1], cqk2, -m0));
        lc0 += FEXP2(fmaf((float)dq0[j][2], cqk2, -m0));
        ld0 += FEXP2(fmaf((float)dq0[j][3], cqk2, -m0));
        la1 += FEXP2(fmaf((float)dq1[j][0], cqk2, -m1));
        lb1 += FEXP2(fmaf((float)dq1[j][1], cqk2, -m1));
        lc1 += FEXP2(fmaf((float)dq1[j][2], cqk2, -m1));
        ld1 += FEXP2(fmaf((float)dq1[j][3], cqk2, -m1));
    }
    float l0 = (la0 + lb0) + (lc0 + ld0);
    float l1 = (la1 + lb1) + (lc1 + ld1);
    l0 += __shfl_xor(l0, 16, 64);
    l0 += __shfl_xor(l0, 32, 64);
    l1 += __shfl_xor(l1, 16, 64);
    l1 += __shfl_xor(l1, 32, 64);
    if (g == 0) {
        Mf[wv][c] = m0;      Lf[wv][c] = l0;
        Mf[wv][16 + c] = m1; Lf[wv][16 + c] = l1;
    }
    __syncthreads();                                   // the ONLY barrier
    if (tid < 32) {
        const int cc = tid;
        float m = Mf[0][cc];
        #pragma unroll
        for (int w = 1; w < 8; ++w) m = fmaxf(m, Mf[w][cc]);
        float l = 0.0f;
        #pragma unroll
        for (int w = 0; w < 8; ++w) l += Lf[w][cc] * FEXP2(Mf[w][cc] - m);
        m2_arr[bn * SS + s0 + cc] = m;
        l_arr[bn * SS + s0 + cc] = l;
        float lm = l;
        #pragma unroll
        for (int mk = 1; mk <= 16; mk <<= 1) lm = fminf(lm, __shfl_xor(lm, mk, 64));
        if (cc == 0) minl_part[blockIdx.y * 64 + blockIdx.x] = lm;   // plain store
    }
}

// Phase B: 8 waves = 4 s-groups x 2 t-halves; K/V LDS double-buffered; quant chain
// exp2 -> rintf -> PK_U8, per-word k2 = (w>>1)&0x7f7f7f7f. Scales and minl derived
// from partials in the preamble (wave-redundant, no atomics).
__global__ __launch_bounds__(512) void k_phase_b(const int* __restrict__ Qp,
    const int* __restrict__ Kp, const int* __restrict__ Vq,
    const float* __restrict__ amax_part, const float* __restrict__ minl_part,
    const float* __restrict__ m2_arr, const float* __restrict__ l_arr,
    float* __restrict__ out)
{
    __shared__ __align__(16) int Kst[2][2][1024];   // [buf][th][tile] 16 KB
    __shared__ __align__(16) int Vst[2][2][1024];   // 16 KB
    __shared__ __align__(16) int PlS[2816];         // Pl (8x320) / epilogue sbuf (32x67)
    const int f = blockIdx.x + (blockIdx.y << 4);
    const int bn = ((f & 7) << 3) | ((f >> 3) & 7);
    const int sblk = (f >> 6) * 64;
    const int tid = threadIdx.x;
    const int wv = tid >> 6, lane = tid & 63;
    const int g = lane >> 4, c = lane & 15;
    const int sgrp = wv & 3, th = wv >> 2;
    const int s0 = sblk + sgrp * 16;
    const float sq = fmaxf(wave_max256(amax_part, lane) / 127.0f, 1e-8f);
    const float sk = fmaxf(wave_max256(amax_part + 256, lane) / 127.0f, 1e-8f);
    const float sv = fmaxf(wave_max256(amax_part + 512, lane) / 127.0f, 1e-8f);
    const float minl = wave_min2048(minl_part, lane);
    const float cqk2 = (sq * sk * 0.125f) * 1.4426950408889634f;
    const float maxP     = 1.0f / minl;
    const float scale_p  = fmaxf(maxP / 255.0f, 1e-8f);
    const float scale_p2 = fmaxf((255.0f * scale_p) / 127.0f, 1e-8f);
    const float cpv = scale_p2 * sv;
    const float m2 = m2_arr[bn * SS + s0 + c];
    const float l  = l_arr [bn * SS + s0 + c];
    const float bexp = log2f((1.0f / scale_p) / l) - m2;   // x = exp2(dq*cqk2 + bexp)
    const i32x4_ qf = *(const i32x4_*)(Qp + ((size_t)bn * SS + s0 + c) * 16 + g * 4);
    const i32x4_ zero = {0, 0, 0, 0};
    int* myP = PlS + wv * 320;
    const int woff = c * 20 + g * 4;
    const int tb0 = th * 8;
    const int soff = sgrp * 256 + lane * 4;
    const int* kg = Kp + (size_t)bn * SS * 16 + soff;   // + tb*1024
    const int* vg = Vq + (size_t)bn * 16384 + soff;     // + tb*1024

    i32x4_ acc[4] = {zero, zero, zero, zero};

    {   // prologue: stage tb0 into buf 0
        i32x4_ gk = *(const i32x4_*)(kg + tb0 * 1024);
        i32x4_ gv = *(const i32x4_*)(vg + tb0 * 1024);
        *(i32x4_*)&Kst[0][th][soff] = gk;
        *(i32x4_*)&Vst[0][th][soff] = gv;
    }
    __syncthreads();

    #pragma unroll
    for (int i = 0; i < 8; ++i) {
        const int b = i & 1;
        i32x4_ gk, gv;
        if (i < 7) {                                   // issue next tile's loads early
            gk = *(const i32x4_*)(kg + (tb0 + i + 1) * 1024);
            gv = *(const i32x4_*)(vg + (tb0 + i + 1) * 1024);
        }
        __builtin_amdgcn_sched_barrier(0);
        int W[4];
        #pragma unroll
        for (int j = 0; j < 4; ++j) {                  // QK + quantize P
            i32x4_ kf = *(const i32x4_*)&Kst[b][th][j * 256 + c * 16 + g * 4];
            i32x4_ dq = mfma_i8(kf, qf, zero);
            int w = 0;
            #pragma unroll
            for (int r = 0; r < 4; ++r) {
                float xx = FEXP2(fmaf((float)dq[r], cqk2, bexp));
                w = PK_U8(rintf(xx), r, w);            // k1 byte insert (pre-rounded)
            }
            W[j] = (w >> 1) & 0x7f7f7f7f;              // per-byte k2 = k1>>1
        }
        i32x4_ wv4 = {W[0], W[1], W[2], W[3]};
        *(i32x4_*)(myP + woff) = wv4;                  // publish W(tb)
        i32x4_ pa;                                     // word-transpose read
        pa[0] = myP[c * 20 + 0 + g];
        pa[1] = myP[c * 20 + 4 + g];
        pa[2] = myP[c * 20 + 8 + g];
        pa[3] = myP[c * 20 + 12 + g];
        #pragma unroll
        for (int dt = 0; dt < 4; ++dt) {
            i32x4_ vf = *(const i32x4_*)&Vst[b][th][dt * 256 + g * 64 + c * 4];
            acc[dt] = mfma_i8(pa, vf, acc[dt]);
        }
        if (i < 7) {                                   // land next tile
            *(i32x4_*)&Kst[b ^ 1][th][soff] = gk;
            *(i32x4_*)&Vst[b ^ 1][th][soff] = gv;
        }
        __syncthreads();
    }

    // epilogue: combine t-halves (exact int add) + scale + coalesced store, reusing PlS.
    int* sbuf = PlS;
    #pragma unroll
    for (int ch = 0; ch < 2; ++ch) {
        if (th == 0) {
            #pragma unroll
            for (int dt = 0; dt < 2; ++dt)
                #pragma unroll
                for (int r = 0; r < 4; ++r)
                    sbuf[(dt * 16 + c) * 67 + sgrp * 16 + 4 * g + r] = acc[ch * 2 + dt][r];
        }
        __syncthreads();
        if (th == 1) {
            #pragma unroll
            for (int dt = 0; dt < 2; ++dt)
                #pragma unroll
                for (int r = 0; r < 4; ++r) {
                    const int slot = (dt * 16 + c) * 67 + sgrp * 16 + 4 * g + r;
                    ((float*)sbuf)[slot] = (float)(sbuf[slot] + acc[ch * 2 + dt][r]) * cpv;
                }
        }
        __syncthreads();
        {
            const int d = tid >> 4, sq4 = tid & 15;
            const float* fb = (const float*)sbuf + d * 67 + sq4 * 4;
            float4 val = make_float4(fb[0], fb[1], fb[2], fb[3]);
            *(float4*)(out + (size_t)bn * 65536 + (size_t)(ch * 32 + d) * 1024 + sblk + sq4 * 4) = val;
        }
        __syncthreads();
    }
}

extern "C" void kernel_launch(void* const* d_in, const int* in_sizes, int n_in,
                              void* d_out, int out_size, void* d_ws, size_t ws_size,
                              hipStream_t stream) {
    const float* q = (const float*)d_in[0];
    const float* k = (const float*)d_in[1];
    const float* v = (const float*)d_in[2];
    float* out = (float*)d_out;
    char* ws = (char*)d_ws;

    float* amax_part = (float*)ws;                                // 3*256 floats (partial maxima)
    float* minl_part = (float*)(ws + 4096);                       // 2048 floats
    int* Qp      = (int*)(ws + 16384);                            // 4 MB
    int* Kp      = (int*)(ws + 16384 + (size_t)(1 << 22));        // 4 MB
    int* Vq      = (int*)(ws + 16384 + (size_t)(2 << 22));        // 4 MB
    float* m2    = (float*)(ws + 16384 + (size_t)(3 << 22));      // 256 KB
    float* l_a   = (float*)(ws + 16384 + (size_t)(3 << 22) + (1 << 18)); // 256 KB

    k_absmax<<<dim3(256, 3), 256, 0, stream>>>(q, k, v, amax_part);
    k_quant_qkv<<<dim3(16, NBN, 3), 256, 0, stream>>>(q, k, v, amax_part, Qp, Kp, Vq);
    k_phase_a<<<dim3(64, 32), 512, 0, stream>>>(Qp, Kp, amax_part, m2, l_a, minl_part);
    k_phase_b<<<dim3(16, NBN), 512, 0, stream>>>(Qp, Kp, Vq, amax_part, minl_part, m2, l_a, out);
}